// Round 2
// baseline (7571.307 us; speedup 1.0000x reference)
//
#include <hip/hip_runtime.h>
#include <cmath>

#define TPB 256
constexpr int TX = 128;
constexpr int TY = 8;

// ---------------------------------------------------------------------------
// Generic 3x3 conv, pad=1, NCHW fp32, ONE batch image per launch.
// Tile: TY x TX pixels, 8 output channels per block. 256 threads,
// each thread: 8 co x 4 px accumulators. Input staged in LDS in chunks
// of CI_CHUNK channels. Weight loads are wave-uniform -> scalar loads.
// EPI: 0 = +bias, relu
//      1 = cdc:  relu(conv3x3 - theta * conv1x1(kdiff))   (no bias)
//      2 = res:  in + gamma[co]*(conv3x3 + bias) + beta[co]
// ---------------------------------------------------------------------------
template<int CI, int CI_CHUNK, int EPI>
__global__ __launch_bounds__(TPB) void conv3x3_k(
    const float* __restrict__ in, const float* __restrict__ w,
    const float* __restrict__ bias, float* __restrict__ out,
    int H, int W, int nxt,
    const float* __restrict__ theta,
    const float* __restrict__ gamma, const float* __restrict__ beta)
{
    constexpr int RS = TX + 4;   // LDS row stride (132 floats -> 16B aligned)
    __shared__ float s_in[CI_CHUNK][TY + 2][RS];

    const int tid = threadIdx.x;
    const int tx0 = (blockIdx.x % nxt) * TX;
    const int ty0 = (blockIdx.x / nxt) * TY;
    const int cog = blockIdx.y;
    const int txr = (tid & 31) * 4;   // x offset of this thread's 4-px run
    const int ty  = tid >> 5;         // row within tile

    float acc[8][4];
    float accd[8][4];
    #pragma unroll
    for (int co = 0; co < 8; ++co)
        #pragma unroll
        for (int px = 0; px < 4; ++px) { acc[co][px] = 0.f; accd[co][px] = 0.f; }

    for (int ci0 = 0; ci0 < CI; ci0 += CI_CHUNK) {
        __syncthreads();
        constexpr int SROW = TX + 2;
        constexpr int STOT = CI_CHUNK * (TY + 2) * SROW;
        for (int i = tid; i < STOT; i += TPB) {
            const int cil = i / ((TY + 2) * SROW);
            const int rem = i % ((TY + 2) * SROW);
            const int r = rem / SROW;
            const int c = rem % SROW;
            const int gy = ty0 - 1 + r;
            const int gx = tx0 - 1 + c;
            float v = 0.f;
            if (gy >= 0 && gy < H && gx >= 0 && gx < W)
                v = in[((size_t)(ci0 + cil) * H + gy) * W + gx];
            s_in[cil][r][c] = v;
        }
        __syncthreads();

        #pragma unroll
        for (int cil = 0; cil < CI_CHUNK; ++cil) {
            const int ci = ci0 + cil;
            float ks[8];
            if constexpr (EPI == 1) {
                #pragma unroll
                for (int co = 0; co < 8; ++co) ks[co] = 0.f;
            }
            #pragma unroll
            for (int dy = 0; dy < 3; ++dy) {
                float wv[8][3];
                #pragma unroll
                for (int co = 0; co < 8; ++co) {
                    const float* wp = w + ((size_t)(cog * 8 + co) * CI + ci) * 9 + dy * 3;
                    wv[co][0] = wp[0]; wv[co][1] = wp[1]; wv[co][2] = wp[2];
                }
                const float4 v4 = *reinterpret_cast<const float4*>(&s_in[cil][ty + dy][txr]);
                const float2 v2 = *reinterpret_cast<const float2*>(&s_in[cil][ty + dy][txr + 4]);
                const float xv[6] = {v4.x, v4.y, v4.z, v4.w, v2.x, v2.y};
                #pragma unroll
                for (int dx = 0; dx < 3; ++dx)
                    #pragma unroll
                    for (int px = 0; px < 4; ++px)
                        #pragma unroll
                        for (int co = 0; co < 8; ++co)
                            acc[co][px] = fmaf(wv[co][dx], xv[px + dx], acc[co][px]);
                if constexpr (EPI == 1) {
                    #pragma unroll
                    for (int co = 0; co < 8; ++co)
                        ks[co] += wv[co][0] + wv[co][1] + wv[co][2];
                }
            }
            if constexpr (EPI == 1) {
                float xc[4];
                #pragma unroll
                for (int px = 0; px < 4; ++px) xc[px] = s_in[cil][ty + 1][txr + 1 + px];
                #pragma unroll
                for (int co = 0; co < 8; ++co)
                    #pragma unroll
                    for (int px = 0; px < 4; ++px)
                        accd[co][px] = fmaf(ks[co], xc[px], accd[co][px]);
            }
        }
    }

    const int y  = ty0 + ty;
    const int x0 = tx0 + txr;
    float th = 0.f;
    if constexpr (EPI == 1) th = theta[0];
    #pragma unroll
    for (int co = 0; co < 8; ++co) {
        const int oc = cog * 8 + co;
        const size_t base = ((size_t)oc * H + y) * W + x0;
        float g = 0.f, be = 0.f, bi = 0.f;
        if constexpr (EPI == 2) { g = gamma[oc]; be = beta[oc]; }
        if constexpr (EPI != 1) bi = bias[oc];
        #pragma unroll
        for (int px = 0; px < 4; ++px) {
            float v;
            if constexpr (EPI == 0) {
                v = fmaxf(acc[co][px] + bi, 0.f);
            } else if constexpr (EPI == 1) {
                v = fmaxf(acc[co][px] - th * accd[co][px], 0.f);
            } else {
                const float deco = in[base + px];
                v = deco + g * (acc[co][px] + bi) + be;
            }
            out[base + px] = v;
        }
    }
}

// ---------------------------------------------------------------------------
// d2 conv (32 -> 1) + tanh + enhancement for ONE batch image.
// ---------------------------------------------------------------------------
__global__ __launch_bounds__(TPB) void d2_enhance_k(
    const float* __restrict__ f, const float* __restrict__ x,
    const float* __restrict__ w, const float* __restrict__ bias,
    float* __restrict__ outE, float* __restrict__ outM, int H, int W, int nxt)
{
    constexpr int RS = TX + 4;
    __shared__ float s_in[8][TY + 2][RS];

    const int tid = threadIdx.x;
    const int tx0 = (blockIdx.x % nxt) * TX;
    const int ty0 = (blockIdx.x / nxt) * TY;
    const int txr = (tid & 31) * 4;
    const int ty  = tid >> 5;

    float acc[4] = {0.f, 0.f, 0.f, 0.f};

    for (int ci0 = 0; ci0 < 32; ci0 += 8) {
        __syncthreads();
        constexpr int SROW = TX + 2;
        constexpr int STOT = 8 * (TY + 2) * SROW;
        for (int i = tid; i < STOT; i += TPB) {
            const int cil = i / ((TY + 2) * SROW);
            const int rem = i % ((TY + 2) * SROW);
            const int r = rem / SROW;
            const int c = rem % SROW;
            const int gy = ty0 - 1 + r;
            const int gx = tx0 - 1 + c;
            float v = 0.f;
            if (gy >= 0 && gy < H && gx >= 0 && gx < W)
                v = f[((size_t)(ci0 + cil) * H + gy) * W + gx];
            s_in[cil][r][c] = v;
        }
        __syncthreads();

        #pragma unroll
        for (int cil = 0; cil < 8; ++cil) {
            const int ci = ci0 + cil;
            #pragma unroll
            for (int dy = 0; dy < 3; ++dy) {
                float wv[3];
                wv[0] = w[ci * 9 + dy * 3 + 0];
                wv[1] = w[ci * 9 + dy * 3 + 1];
                wv[2] = w[ci * 9 + dy * 3 + 2];
                const float4 v4 = *reinterpret_cast<const float4*>(&s_in[cil][ty + dy][txr]);
                const float2 v2 = *reinterpret_cast<const float2*>(&s_in[cil][ty + dy][txr + 4]);
                const float xv[6] = {v4.x, v4.y, v4.z, v4.w, v2.x, v2.y};
                #pragma unroll
                for (int dx = 0; dx < 3; ++dx)
                    #pragma unroll
                    for (int px = 0; px < 4; ++px)
                        acc[px] = fmaf(wv[dx], xv[px + dx], acc[px]);
            }
        }
    }

    const int y  = ty0 + ty;
    const int x0 = tx0 + txr;
    const size_t mapbase = (size_t)y * W + x0;
    const float b0 = bias[0];
    #pragma unroll
    for (int px = 0; px < 4; ++px) {
        const float om = tanhf(acc[px] + b0);
        outM[mapbase + px] = om;
        #pragma unroll
        for (int c = 0; c < 3; ++c) {
            const size_t xi = ((size_t)c * H + y) * W + x0 + px;
            const float xv = x[xi];
            outE[xi] = xv + om * (xv * xv - xv);
        }
    }
}

// ---------------------------------------------------------------------------
// Haar DWT (all 4 batches): x (4,3,512,512) -> haarA (4,3,256,256),
// hf (4,9,256,256) with layout [LH c0..c2, HL c0..c2, HH c0..c2]
// ---------------------------------------------------------------------------
__global__ __launch_bounds__(TPB) void dwt_k(
    const float* __restrict__ x, float* __restrict__ haarA, float* __restrict__ hf)
{
    const int idx = blockIdx.x * TPB + threadIdx.x;
    if (idx >= 4 * 256 * 256) return;
    const int xo = idx & 255;
    const int yo = (idx >> 8) & 255;
    const int b  = idx >> 16;
    #pragma unroll
    for (int c = 0; c < 3; ++c) {
        const float* p = x + (((size_t)b * 3 + c) * 512 + 2 * yo) * 512 + 2 * xo;
        const float a = p[0], bb = p[1], cc = p[512], d = p[513];
        haarA[(((size_t)b * 3 + c) * 256 + yo) * 256 + xo] = 0.5f * (a + bb + cc + d);
        hf[(((size_t)b * 9 + 0 + c) * 256 + yo) * 256 + xo] = 0.5f * (a + bb - cc - d);
        hf[(((size_t)b * 9 + 3 + c) * 256 + yo) * 256 + xo] = 0.5f * (a - bb + cc - d);
        hf[(((size_t)b * 9 + 6 + c) * 256 + yo) * 256 + xo] = 0.5f * (a - bb - cc + d);
    }
}

// ---------------------------------------------------------------------------
// Chunked spatial mean, one batch: stage 1 partial sums, stage 2 finish.
// in: (C, HW) contiguous. grid (C, CH), HWc = HW/CH.
// ---------------------------------------------------------------------------
__global__ __launch_bounds__(TPB) void mean_part_k(
    const float* __restrict__ in, float* __restrict__ part, int HWc)
{
    const int c = blockIdx.x, ch = blockIdx.y, CH = gridDim.y;
    const float* p = in + ((size_t)c * CH + ch) * HWc;
    float s = 0.f;
    for (int i = threadIdx.x; i < HWc; i += TPB) s += p[i];
    #pragma unroll
    for (int o = 32; o > 0; o >>= 1) s += __shfl_down(s, o, 64);
    __shared__ float red[4];
    const int lane = threadIdx.x & 63, wid = threadIdx.x >> 6;
    if (lane == 0) red[wid] = s;
    __syncthreads();
    if (threadIdx.x == 0) part[c * CH + ch] = red[0] + red[1] + red[2] + red[3];
}

__global__ __launch_bounds__(64) void mean_fin_k(
    const float* __restrict__ part, float* __restrict__ out, int CH, float inv, int C)
{
    const int c = threadIdx.x;
    if (c >= C) return;
    float s = 0.f;
    for (int k = 0; k < CH; ++k) s += part[c * CH + k];
    out[c] = s * inv;
}

// ---------------------------------------------------------------------------
// t1->t2->t3 chain on one batch's (64,) mean -> theta scalar. 64 threads.
// ---------------------------------------------------------------------------
__global__ __launch_bounds__(64) void tchain1_k(
    const float* __restrict__ am,
    const float* __restrict__ t1w, const float* __restrict__ t1b,
    const float* __restrict__ t2w, const float* __restrict__ t2b,
    const float* __restrict__ t3w, const float* __restrict__ t3b,
    float* __restrict__ theta)
{
    __shared__ float a0[64], a1[64], a2[64];
    const int co = threadIdx.x;
    a0[co] = am[co];
    __syncthreads();
    float s = t1b[co];
    #pragma unroll 8
    for (int ci = 0; ci < 64; ++ci) s = fmaf(t1w[co * 64 + ci], a0[ci], s);
    a1[co] = fmaxf(s, 0.f);
    __syncthreads();
    s = t2b[co];
    #pragma unroll 8
    for (int ci = 0; ci < 64; ++ci) s = fmaf(t2w[co * 64 + ci], a1[ci], s);
    a2[co] = fmaxf(s, 0.f);
    __syncthreads();
    if (co == 0) {
        float v = t3b[0];
        for (int ci = 0; ci < 64; ++ci) v = fmaf(t3w[ci], a2[ci], v);
        theta[0] = 1.f / (1.f + expf(-v));
    }
}

// ---------------------------------------------------------------------------
// FC for one batch row: out[co] = act(w[co,:]@in + bias[co]). ACT 0=relu 1=sigmoid
// ---------------------------------------------------------------------------
template<int ACT>
__global__ __launch_bounds__(TPB) void fcb_k(
    const float* __restrict__ in, const float* __restrict__ w,
    const float* __restrict__ bias, float* __restrict__ out, int K, int N)
{
    const int co = blockIdx.x * TPB + threadIdx.x;
    if (co >= N) return;
    float s = bias[co];
    const float* wr = w + (size_t)co * K;
    for (int k = 0; k < K; ++k) s = fmaf(wr[k], in[k], s);
    out[co] = (ACT == 1) ? 1.f / (1.f + expf(-s)) : fmaxf(s, 0.f);
}

// ---------------------------------------------------------------------------
// gamma/beta heads from one batch's am3 (512,). 64 threads.
// ---------------------------------------------------------------------------
__global__ __launch_bounds__(64) void gb1_k(
    const float* __restrict__ am,
    const float* __restrict__ gw, const float* __restrict__ gbias,
    const float* __restrict__ bw, const float* __restrict__ bbias,
    float* __restrict__ gamma, float* __restrict__ beta)
{
    const int t = threadIdx.x;
    const int which = t >> 5;
    const int co = t & 31;
    const float* w  = which ? bw : gw;
    const float* bi = which ? bbias : gbias;
    float s = bi[co];
    const float* wr = w + (size_t)co * 512;
    for (int ci = 0; ci < 512; ++ci) s = fmaf(wr[ci], am[ci], s);
    if (which) beta[co] = tanhf(s);
    else       gamma[co] = 1.f / (1.f + expf(-s));
}

// ---------------------------------------------------------------------------
extern "C" void kernel_launch(void* const* d_in, const int* in_sizes, int n_in,
                              void* d_out, int out_size, void* d_ws, size_t ws_size,
                              hipStream_t stream)
{
    const float* x      = (const float*)d_in[0];
    const float* enc_w[5] = {(const float*)d_in[1], (const float*)d_in[3], (const float*)d_in[5],
                             (const float*)d_in[7], (const float*)d_in[9]};
    const float* enc_b[5] = {(const float*)d_in[2], (const float*)d_in[4], (const float*)d_in[6],
                             (const float*)d_in[8], (const float*)d_in[10]};
    const float* cdc_w  = (const float*)d_in[11];
    const float* ct_w   = (const float*)d_in[12];
    const float* ct_b   = (const float*)d_in[13];
    const float* t1_w   = (const float*)d_in[14];
    const float* t1_b   = (const float*)d_in[15];
    const float* t2_w   = (const float*)d_in[16];
    const float* t2_b   = (const float*)d_in[17];
    const float* t3_w   = (const float*)d_in[18];
    const float* t3_b   = (const float*)d_in[19];
    const float* lf_w   = (const float*)d_in[20];
    const float* lf_b   = (const float*)d_in[21];
    const float* fc1_w  = (const float*)d_in[22];
    const float* fc1_b  = (const float*)d_in[23];
    const float* fc2_w  = (const float*)d_in[24];
    const float* fc2_b  = (const float*)d_in[25];
    const float* fc3_w  = (const float*)d_in[26];
    const float* fc3_b  = (const float*)d_in[27];
    const float* g_w    = (const float*)d_in[28];
    const float* g_b    = (const float*)d_in[29];
    const float* be_w   = (const float*)d_in[30];
    const float* be_b   = (const float*)d_in[31];
    const float* res_w  = (const float*)d_in[32];
    const float* res_b  = (const float*)d_in[33];
    const float* d1_w   = (const float*)d_in[34];
    const float* d1_b   = (const float*)d_in[35];
    const float* d2_w   = (const float*)d_in[36];
    const float* d2_b   = (const float*)d_in[37];

    float* out = (float*)d_out;

    const int HW  = 512 * 512;   // 262144
    const int HW4 = 256 * 256;   // 65536

    // workspace layout (floats) — per-batch ping-pong, ~80 MB total
    float* A     = (float*)d_ws;          // 8,388,608  (32,512,512)
    float* Bb    = A + 8388608;           // 8,388,608  (32,512,512) / (64,256,256)
    float* haarA = Bb + 8388608;          // 786,432    (4,3,256,256)
    float* hf    = haarA + 786432;        // 2,359,296  (4,9,256,256)
    float* amean = hf + 2359296;          // 64
    float* am0   = amean + 64;            // 64
    float* am1   = am0 + 64;              // 512
    float* am2   = am1 + 512;             // 512
    float* am3   = am2 + 512;             // 512
    float* theta = am3 + 512;             // 4
    float* gamma = theta + 4;             // 32
    float* beta  = gamma + 32;            // 32
    float* part  = beta + 32;             // 512
    const size_t need_bytes = (size_t)(part + 512 - (float*)d_ws) * sizeof(float);
    if (ws_size < need_bytes) return;  // diagnostic: leaves d_out poisoned instead of faulting

    const dim3 blk(TPB);
    const int nxt512 = 512 / TX;                    // 4
    const int nt512  = nxt512 * (512 / TY);         // 256
    const int nxt256 = 256 / TX;                    // 2
    const int nt256  = nxt256 * (256 / TY);         // 64
    const int CH = 8, HWc = HW4 / CH;               // 8192

    // 1. DWT for all batches (small buffers)
    dwt_k<<<dim3((4 * 256 * 256 + TPB - 1) / TPB), blk, 0, stream>>>(x, haarA, hf);

    for (int b = 0; b < 4; ++b) {
        const float* xb  = x + (size_t)b * 3 * HW;
        const float* hfb = hf + (size_t)b * 9 * HW4;
        const float* hab = haarA + (size_t)b * 3 * HW4;
        float* outE = out + (size_t)b * 3 * HW;
        float* outM = out + (size_t)4 * 3 * HW + (size_t)b * HW;

        // 2. encoder chain (ping-pong A/B) -> A = f_org4
        conv3x3_k<3, 3, 0><<<dim3(nt512, 4), blk, 0, stream>>>(xb, enc_w[0], enc_b[0], A, 512, 512, nxt512, nullptr, nullptr, nullptr);
        conv3x3_k<32, 8, 0><<<dim3(nt512, 4), blk, 0, stream>>>(A, enc_w[1], enc_b[1], Bb, 512, 512, nxt512, nullptr, nullptr, nullptr);
        conv3x3_k<32, 8, 0><<<dim3(nt512, 4), blk, 0, stream>>>(Bb, enc_w[2], enc_b[2], A, 512, 512, nxt512, nullptr, nullptr, nullptr);
        conv3x3_k<32, 8, 0><<<dim3(nt512, 4), blk, 0, stream>>>(A, enc_w[3], enc_b[3], Bb, 512, 512, nxt512, nullptr, nullptr, nullptr);
        conv3x3_k<32, 8, 0><<<dim3(nt512, 4), blk, 0, stream>>>(Bb, enc_w[4], enc_b[4], A, 512, 512, nxt512, nullptr, nullptr, nullptr);

        // 3. texture attention: ct conv on hf -> B (64,256,256), mean, t-chain -> theta
        conv3x3_k<9, 9, 0><<<dim3(nt256, 8), blk, 0, stream>>>(hfb, ct_w, ct_b, Bb, 256, 256, nxt256, nullptr, nullptr, nullptr);
        mean_part_k<<<dim3(64, CH), blk, 0, stream>>>(Bb, part, HWc);
        mean_fin_k<<<dim3(1), dim3(64), 0, stream>>>(part, amean, CH, 1.f / HW4, 64);
        tchain1_k<<<dim3(1), dim3(64), 0, stream>>>(amean, t1_w, t1_b, t2_w, t2_b, t3_w, t3_b, theta);

        // 4. low-freq branch: lf conv on haarA -> B (64,256,256), mean, FC chain
        conv3x3_k<3, 3, 0><<<dim3(nt256, 8), blk, 0, stream>>>(hab, lf_w, lf_b, Bb, 256, 256, nxt256, nullptr, nullptr, nullptr);
        mean_part_k<<<dim3(64, CH), blk, 0, stream>>>(Bb, part, HWc);
        mean_fin_k<<<dim3(1), dim3(64), 0, stream>>>(part, am0, CH, 1.f / HW4, 64);
        fcb_k<0><<<dim3(2), blk, 0, stream>>>(am0, fc1_w, fc1_b, am1, 64, 512);
        fcb_k<0><<<dim3(2), blk, 0, stream>>>(am1, fc2_w, fc2_b, am2, 512, 512);
        fcb_k<1><<<dim3(2), blk, 0, stream>>>(am2, fc3_w, fc3_b, am3, 512, 512);
        gb1_k<<<dim3(1), dim3(64), 0, stream>>>(am3, g_w, g_b, be_w, be_b, gamma, beta);

        // 5. cdc: f_deco = relu(conv(A) - theta*conv1x1(A)) -> B
        conv3x3_k<32, 8, 1><<<dim3(nt512, 4), blk, 0, stream>>>(A, cdc_w, nullptr, Bb, 512, 512, nxt512, theta, nullptr, nullptr);

        // 6. res: f = f_deco + gamma*(conv(f_deco)+res_b) + beta -> A
        conv3x3_k<32, 8, 2><<<dim3(nt512, 4), blk, 0, stream>>>(Bb, res_w, res_b, A, 512, 512, nxt512, nullptr, gamma, beta);

        // 7. d1: relu conv -> B
        conv3x3_k<32, 8, 0><<<dim3(nt512, 4), blk, 0, stream>>>(A, d1_w, d1_b, Bb, 512, 512, nxt512, nullptr, nullptr, nullptr);

        // 8. d2 + tanh + enhance -> d_out
        d2_enhance_k<<<dim3(nt512), blk, 0, stream>>>(Bb, xb, d2_w, d2_b, outE, outM, 512, 512, nxt512);
    }
}

// Round 3
// 1099.015 us; speedup vs baseline: 6.8892x; 6.8892x over previous
//
#include <hip/hip_runtime.h>
#include <hip/hip_bf16.h>
#include <cmath>

#define TPB 256

typedef __attribute__((ext_vector_type(8))) short s16x8;
typedef __attribute__((ext_vector_type(4))) float f32x4;

static __device__ __forceinline__ short f2bf(float f) {
    __hip_bfloat16 h = __float2bfloat16(f);
    union { __hip_bfloat16 h; short s; } u;
    u.h = h;
    return u.s;
}

#define COMP(vec,k) ((k)==0?(vec).x:((k)==1?(vec).y:((k)==2?(vec).z:(vec).w)))

// ---------------------------------------------------------------------------
// Weight pack: OIHW fp32 -> per-lane MFMA A-fragments (bf16), + fp32 bias.
// Layout: shorts[((t*2+mt)*64 + lane)*8 + i] = w[co = cog*32+16*mt+(lane&15)]
//                                              [ci = 8*(lane>>4)+i][t]
// cdc fold: center tap (t==4) -= theta * sum_t w   (== conv3x3 - theta*conv1x1(kdiff))
// bias fp32[32] at short-offset 9216. Slot stride 10240 shorts.
// ---------------------------------------------------------------------------
__global__ __launch_bounds__(64) void pack_k(
    const float* __restrict__ w, const float* __restrict__ bias,
    const float* __restrict__ theta, short* __restrict__ dst0, int CO, int CI)
{
    const int cog = blockIdx.x;
    short* dst = dst0 + (size_t)cog * 10240;
    const int l = threadIdx.x;
    const int l15 = l & 15, sl = l >> 4;
    for (int t = 0; t < 9; ++t) {
        for (int mt = 0; mt < 2; ++mt) {
            const int co = cog * 32 + 16 * mt + l15;
            s16x8 p;
            #pragma unroll
            for (int i = 0; i < 8; ++i) {
                const int ci = 8 * sl + i;
                float val = 0.f;
                if (co < CO && ci < CI) {
                    val = w[((size_t)co * CI + ci) * 9 + t];
                    if (theta && t == 4) {
                        float s = 0.f;
                        for (int tt = 0; tt < 9; ++tt) s += w[((size_t)co * CI + ci) * 9 + tt];
                        val -= theta[0] * s;
                    }
                }
                p[i] = f2bf(val);
            }
            *(s16x8*)(dst + ((size_t)(t * 2 + mt) * 64 + l) * 8) = p;
        }
    }
    if (l < 32) {
        const int co = cog * 32 + l;
        float bv = (bias && co < CO) ? bias[co] : 0.f;
        ((float*)(dst + 9216))[l] = bv;
    }
}

// ---------------------------------------------------------------------------
// MFMA conv 3x3 pad=1, K = ci padded to 32 (one mfma K-step per tap).
// Block: 256 thr = 4 waves. Tile: 128 px wide x 4 rows, all 32 co (per cog).
// Wave w: x-seg [32w, 32w+32), rows processed in pairs (2 acc sets).
// LDS: bf16 [6 rows][130 x][32 ci], 64 B/entry, slot-swizzled:
//   slot' = slot ^ ((lx + (lx>>2)) & 3)   (slot = 16B ci-octet)
// A = weights (regs, packed), B = input (LDS). D[m=co][n=x] -> coalesced store.
// EPI: 0 bias+relu | 2 res: in + gamma[co]*(acc+bias) + beta[co] | 3 d2+enhance
// ---------------------------------------------------------------------------
template<int EPI>
__global__ __launch_bounds__(TPB) void conv16_k(
    const float* __restrict__ in0, const short* __restrict__ wpack0,
    float* __restrict__ out0, int CI, int H, int W, int ntx,
    long long bstr_in, long long bstr_out,
    const float* __restrict__ gamma, const float* __restrict__ beta,
    const float* __restrict__ xorig, float* __restrict__ outM)
{
    constexpr int RSX = 130;
    constexpr int ROWB = RSX * 64;
    __shared__ s16x8 lds_t[6 * RSX * 4];   // 49,920 B
    char* sb = (char*)lds_t;

    const int tid  = threadIdx.x;
    const int lane = tid & 63;
    const int wv   = tid >> 6;
    const float* in = in0 + (size_t)blockIdx.z * bstr_in;
    float* out      = out0 + (size_t)blockIdx.z * bstr_out;
    const int cog  = blockIdx.y;
    const short* wslot = wpack0 + (size_t)cog * 10240;
    const int tx = blockIdx.x % ntx, tyb = blockIdx.x / ntx;
    const int x0g = tx * 128, y0 = tyb * 4;
    const size_t HW = (size_t)H * W;

    // --- weight fragments (18 x dwordx4, coalesced) ---
    s16x8 wf[9][2];
    #pragma unroll
    for (int t = 0; t < 9; ++t)
        #pragma unroll
        for (int mt = 0; mt < 2; ++mt)
            wf[t][mt] = *(const s16x8*)(wslot + ((size_t)(t * 2 + mt) * 64 + lane) * 8);

    // --- stage interior: 6 rows x 4 ci-octets x 32 xq -> 768 tasks ---
    for (int q = tid; q < 768; q += TPB) {
        const int xq = q & 31, o = (q >> 5) & 3, row = q >> 7;
        const int gy = y0 - 1 + row;
        const bool yok = (gy >= 0) && (gy < H);
        const float* gp = in + (size_t)gy * W + x0g + 4 * xq;
        float4 v[8];
        #pragma unroll
        for (int j = 0; j < 8; ++j) {
            const int ci = 8 * o + j;
            if (yok && ci < CI) v[j] = *(const float4*)(gp + (size_t)ci * HW);
            else                v[j] = make_float4(0.f, 0.f, 0.f, 0.f);
        }
        #pragma unroll
        for (int k = 0; k < 4; ++k) {
            const int lx = 1 + 4 * xq + k;
            const int vs = (lx + (lx >> 2)) & 3;
            const int addr = (row * RSX + lx) * 64 + ((o ^ vs) << 4);
            s16x8 p;
            #pragma unroll
            for (int j = 0; j < 8; ++j) p[j] = f2bf(COMP(v[j], k));
            *(s16x8*)(sb + addr) = p;
        }
    }
    // --- halo columns lx=0, lx=129: 6 rows x 4 octets x 2 sides = 48 tasks ---
    if (tid < 48) {
        const int side = tid & 1, o = (tid >> 1) & 3, row = tid >> 3;
        const int gy = y0 - 1 + row;
        const int lx = side ? 129 : 0;
        const int gx = x0g + (side ? 128 : -1);
        const bool ok = (gy >= 0) && (gy < H) && (gx >= 0) && (gx < W);
        s16x8 p;
        #pragma unroll
        for (int j = 0; j < 8; ++j) {
            const int ci = 8 * o + j;
            float f = (ok && ci < CI) ? in[(size_t)ci * HW + (size_t)gy * W + gx] : 0.f;
            p[j] = f2bf(f);
        }
        const int vs = (lx + (lx >> 2)) & 3;
        *(s16x8*)(sb + (row * RSX + lx) * 64 + ((o ^ vs) << 4)) = p;
    }
    __syncthreads();

    // --- per-lane LDS read offsets (B-fragment) ---
    const int xw = 32 * wv;
    const int l15 = lane & 15, slot = lane >> 4;
    int roff[3][2];
    #pragma unroll
    for (int dx = 0; dx < 3; ++dx)
        #pragma unroll
        for (int nt = 0; nt < 2; ++nt) {
            const int lx = xw + 16 * nt + dx + l15;
            const int vs = (lx + (lx >> 2)) & 3;
            roff[dx][nt] = lx * 64 + ((slot ^ vs) << 4);
        }

    const float* bptr = (const float*)(wslot + 9216);

    for (int r2 = 0; r2 < 4; r2 += 2) {
        f32x4 acc[2][2][2];  // [row][mt][nt]
        #pragma unroll
        for (int a = 0; a < 2; ++a)
            #pragma unroll
            for (int b = 0; b < 2; ++b)
                #pragma unroll
                for (int c = 0; c < 2; ++c)
                    #pragma unroll
                    for (int e = 0; e < 4; ++e) acc[a][b][c][e] = 0.f;

        #pragma unroll
        for (int dy = 0; dy < 3; ++dy) {
            const int rb0 = (r2 + dy) * ROWB;
            #pragma unroll
            for (int dx = 0; dx < 3; ++dx) {
                const int t = dy * 3 + dx;
                #pragma unroll
                for (int nt = 0; nt < 2; ++nt) {
                    const s16x8 b0 = *(const s16x8*)(sb + rb0 + roff[dx][nt]);
                    const s16x8 b1 = *(const s16x8*)(sb + rb0 + ROWB + roff[dx][nt]);
                    #pragma unroll
                    for (int mt = 0; mt < 2; ++mt) {
                        acc[0][mt][nt] = __builtin_amdgcn_mfma_f32_16x16x32_bf16(wf[t][mt], b0, acc[0][mt][nt], 0, 0, 0);
                        acc[1][mt][nt] = __builtin_amdgcn_mfma_f32_16x16x32_bf16(wf[t][mt], b1, acc[1][mt][nt], 0, 0, 0);
                    }
                }
            }
        }

        // --- epilogue: C/D layout col=lane&15 (x), row=(lane>>4)*4+reg (co) ---
        #pragma unroll
        for (int rr = 0; rr < 2; ++rr) {
            const int gy = y0 + r2 + rr;
            if constexpr (EPI == 3) {
                if (slot == 0) {
                    const float b0v = bptr[0];
                    #pragma unroll
                    for (int nt = 0; nt < 2; ++nt) {
                        const float om = tanhf(acc[rr][0][nt][0] + b0v);
                        const int gx = x0g + xw + 16 * nt + l15;
                        outM[(size_t)gy * W + gx] = om;
                        #pragma unroll
                        for (int c = 0; c < 3; ++c) {
                            const size_t xi = ((size_t)c * H + gy) * W + gx;
                            const float xv = xorig[xi];
                            out[xi] = xv + om * (xv * xv - xv);
                        }
                    }
                }
            } else {
                #pragma unroll
                for (int mt = 0; mt < 2; ++mt)
                    #pragma unroll
                    for (int nt = 0; nt < 2; ++nt) {
                        const int gx = x0g + xw + 16 * nt + l15;
                        #pragma unroll
                        for (int reg = 0; reg < 4; ++reg) {
                            const int co = 16 * mt + 4 * slot + reg;
                            const size_t off = (size_t)(cog * 32 + co) * HW + (size_t)gy * W + gx;
                            float v = acc[rr][mt][nt][reg] + bptr[co];
                            if constexpr (EPI == 0) {
                                v = fmaxf(v, 0.f);
                            } else {  // EPI == 2
                                v = in[off] + gamma[co] * v + beta[co];
                            }
                            out[off] = v;
                        }
                    }
            }
        }
    }
}

// ---------------------------------------------------------------------------
// Haar DWT (all 4 batches)
// ---------------------------------------------------------------------------
__global__ __launch_bounds__(TPB) void dwt_k(
    const float* __restrict__ x, float* __restrict__ haarA, float* __restrict__ hf)
{
    const int idx = blockIdx.x * TPB + threadIdx.x;
    if (idx >= 4 * 256 * 256) return;
    const int xo = idx & 255;
    const int yo = (idx >> 8) & 255;
    const int b  = idx >> 16;
    #pragma unroll
    for (int c = 0; c < 3; ++c) {
        const float* p = x + (((size_t)b * 3 + c) * 512 + 2 * yo) * 512 + 2 * xo;
        const float a = p[0], bb = p[1], cc = p[512], d = p[513];
        haarA[(((size_t)b * 3 + c) * 256 + yo) * 256 + xo] = 0.5f * (a + bb + cc + d);
        hf[(((size_t)b * 9 + 0 + c) * 256 + yo) * 256 + xo] = 0.5f * (a + bb - cc - d);
        hf[(((size_t)b * 9 + 3 + c) * 256 + yo) * 256 + xo] = 0.5f * (a - bb + cc - d);
        hf[(((size_t)b * 9 + 6 + c) * 256 + yo) * 256 + xo] = 0.5f * (a - bb - cc + d);
    }
}

// ---------------------------------------------------------------------------
// Chunked spatial mean over rows of length HWc (grid: (nrows, CH))
// ---------------------------------------------------------------------------
__global__ __launch_bounds__(TPB) void mean_part_k(
    const float* __restrict__ in, float* __restrict__ part, int HWc)
{
    const int c = blockIdx.x, ch = blockIdx.y, CH = gridDim.y;
    const float* p = in + ((size_t)c * CH + ch) * HWc;
    float s = 0.f;
    for (int i = threadIdx.x; i < HWc; i += TPB) s += p[i];
    #pragma unroll
    for (int o = 32; o > 0; o >>= 1) s += __shfl_down(s, o, 64);
    __shared__ float red[4];
    const int lane = threadIdx.x & 63, wid = threadIdx.x >> 6;
    if (lane == 0) red[wid] = s;
    __syncthreads();
    if (threadIdx.x == 0) part[c * CH + ch] = red[0] + red[1] + red[2] + red[3];
}

__global__ __launch_bounds__(TPB) void mean_fin_k(
    const float* __restrict__ part, float* __restrict__ out, int CH, float inv, int C)
{
    const int c = threadIdx.x + blockIdx.x * TPB;
    if (c >= C) return;
    float s = 0.f;
    for (int k = 0; k < CH; ++k) s += part[c * CH + k];
    out[c] = s * inv;
}

// ---------------------------------------------------------------------------
// t1->t2->t3 chain, batched: blockIdx.x = b
// ---------------------------------------------------------------------------
__global__ __launch_bounds__(64) void tchain_k(
    const float* __restrict__ amean,
    const float* __restrict__ t1w, const float* __restrict__ t1b,
    const float* __restrict__ t2w, const float* __restrict__ t2b,
    const float* __restrict__ t3w, const float* __restrict__ t3b,
    float* __restrict__ theta)
{
    const int b = blockIdx.x;
    const float* am = amean + b * 64;
    __shared__ float a0[64], a1[64], a2[64];
    const int co = threadIdx.x;
    a0[co] = am[co];
    __syncthreads();
    float s = t1b[co];
    #pragma unroll 8
    for (int ci = 0; ci < 64; ++ci) s = fmaf(t1w[co * 64 + ci], a0[ci], s);
    a1[co] = fmaxf(s, 0.f);
    __syncthreads();
    s = t2b[co];
    #pragma unroll 8
    for (int ci = 0; ci < 64; ++ci) s = fmaf(t2w[co * 64 + ci], a1[ci], s);
    a2[co] = fmaxf(s, 0.f);
    __syncthreads();
    if (co == 0) {
        float v = t3b[0];
        for (int ci = 0; ci < 64; ++ci) v = fmaf(t3w[ci], a2[ci], v);
        theta[b] = 1.f / (1.f + expf(-v));
    }
}

// ---------------------------------------------------------------------------
// FC batched (B=4): out(b,co) = act(w[co,:]@in[b,:] + bias[co])
// ---------------------------------------------------------------------------
template<int ACT>
__global__ __launch_bounds__(TPB) void fc_k(
    const float* __restrict__ in, const float* __restrict__ w,
    const float* __restrict__ bias, float* __restrict__ out, int K, int N)
{
    const int idx = blockIdx.x * TPB + threadIdx.x;
    if (idx >= 4 * N) return;
    const int co = idx % N, b = idx / N;
    float s = bias[co];
    const float* wr = w + (size_t)co * K;
    const float* ir = in + (size_t)b * K;
    for (int k = 0; k < K; ++k) s = fmaf(wr[k], ir[k], s);
    out[b * N + co] = (ACT == 1) ? 1.f / (1.f + expf(-s)) : fmaxf(s, 0.f);
}

// ---------------------------------------------------------------------------
// gamma/beta heads, batched: blockIdx.x = b
// ---------------------------------------------------------------------------
__global__ __launch_bounds__(64) void gb_k(
    const float* __restrict__ am3,
    const float* __restrict__ gw, const float* __restrict__ gbias,
    const float* __restrict__ bw, const float* __restrict__ bbias,
    float* __restrict__ gamma, float* __restrict__ beta)
{
    const int b = blockIdx.x;
    const float* am = am3 + b * 512;
    const int t = threadIdx.x;
    const int which = t >> 5;
    const int co = t & 31;
    const float* w  = which ? bw : gw;
    const float* bi = which ? bbias : gbias;
    float s = bi[co];
    const float* wr = w + (size_t)co * 512;
    for (int ci = 0; ci < 512; ++ci) s = fmaf(wr[ci], am[ci], s);
    if (which) beta[b * 32 + co] = tanhf(s);
    else       gamma[b * 32 + co] = 1.f / (1.f + expf(-s));
}

// ---------------------------------------------------------------------------
extern "C" void kernel_launch(void* const* d_in, const int* in_sizes, int n_in,
                              void* d_out, int out_size, void* d_ws, size_t ws_size,
                              hipStream_t stream)
{
    const float* x      = (const float*)d_in[0];
    const float* enc_w[5] = {(const float*)d_in[1], (const float*)d_in[3], (const float*)d_in[5],
                             (const float*)d_in[7], (const float*)d_in[9]};
    const float* enc_b[5] = {(const float*)d_in[2], (const float*)d_in[4], (const float*)d_in[6],
                             (const float*)d_in[8], (const float*)d_in[10]};
    const float* cdc_w  = (const float*)d_in[11];
    const float* ct_w   = (const float*)d_in[12];
    const float* ct_b   = (const float*)d_in[13];
    const float* t1_w   = (const float*)d_in[14];
    const float* t1_b   = (const float*)d_in[15];
    const float* t2_w   = (const float*)d_in[16];
    const float* t2_b   = (const float*)d_in[17];
    const float* t3_w   = (const float*)d_in[18];
    const float* t3_b   = (const float*)d_in[19];
    const float* lf_w   = (const float*)d_in[20];
    const float* lf_b   = (const float*)d_in[21];
    const float* fc1_w  = (const float*)d_in[22];
    const float* fc1_b  = (const float*)d_in[23];
    const float* fc2_w  = (const float*)d_in[24];
    const float* fc2_b  = (const float*)d_in[25];
    const float* fc3_w  = (const float*)d_in[26];
    const float* fc3_b  = (const float*)d_in[27];
    const float* g_w    = (const float*)d_in[28];
    const float* g_b    = (const float*)d_in[29];
    const float* be_w   = (const float*)d_in[30];
    const float* be_b   = (const float*)d_in[31];
    const float* res_w  = (const float*)d_in[32];
    const float* res_b  = (const float*)d_in[33];
    const float* d1_w   = (const float*)d_in[34];
    const float* d1_b   = (const float*)d_in[35];
    const float* d2_w   = (const float*)d_in[36];
    const float* d2_b   = (const float*)d_in[37];

    float* out = (float*)d_out;

    const int HW  = 512 * 512;
    const int HW4 = 256 * 256;

    // workspace layout (floats)
    float* A     = (float*)d_ws;          // 8,388,608  (32,512,512)  -- A..Bb = 16.7M contiguous
    float* Bb    = A + 8388608;           // 8,388,608
    float* haarA = Bb + 8388608;          // 786,432    (4,3,256,256)
    float* hf    = haarA + 786432;        // 2,359,296  (4,9,256,256)
    float* amean = hf + 2359296;          // 256  [4][64]
    float* am0   = amean + 256;           // 256  [4][64]
    float* am1   = am0 + 256;             // 2048 [4][512]
    float* am2   = am1 + 2048;            // 2048
    float* am3   = am2 + 2048;            // 2048
    float* theta = am3 + 2048;            // 4
    float* gamma = theta + 4;             // 128 [4][32]
    float* beta  = gamma + 128;           // 128
    float* part  = beta + 128;            // 2048 (256 x 8)
    short* wpack = (short*)(part + 2048); // 16 slots x 10240 shorts
    const size_t need_bytes = (size_t)((float*)(wpack + 16 * 10240) - (float*)d_ws) * sizeof(float);
    if (ws_size < need_bytes) return;

    const dim3 blk(TPB);

    // 1. DWT
    dwt_k<<<dim3((4 * 256 * 256 + TPB - 1) / TPB), blk, 0, stream>>>(x, haarA, hf);

    // 2. static weight packs (slots: 0=enc1 1-4=enc2-5 5=res 6=d1 7=d2 8,9=ct 10,11=lf 12-15=cdc[b])
    pack_k<<<1, 64, 0, stream>>>(enc_w[0], enc_b[0], nullptr, wpack + 0 * 10240, 32, 3);
    for (int i = 1; i < 5; ++i)
        pack_k<<<1, 64, 0, stream>>>(enc_w[i], enc_b[i], nullptr, wpack + i * 10240, 32, 32);
    pack_k<<<1, 64, 0, stream>>>(res_w, res_b, nullptr, wpack + 5 * 10240, 32, 32);
    pack_k<<<1, 64, 0, stream>>>(d1_w, d1_b, nullptr, wpack + 6 * 10240, 32, 32);
    pack_k<<<1, 64, 0, stream>>>(d2_w, d2_b, nullptr, wpack + 7 * 10240, 1, 32);
    pack_k<<<2, 64, 0, stream>>>(ct_w, ct_b, nullptr, wpack + 8 * 10240, 64, 9);
    pack_k<<<2, 64, 0, stream>>>(lf_w, lf_b, nullptr, wpack + 10 * 10240, 64, 3);

    // 3. phase A (batched over z): ct conv -> AB, means, tchain -> theta[4]
    conv16_k<0><<<dim3(128, 2, 4), blk, 0, stream>>>(hf, wpack + 8 * 10240, A, 9, 256, 256, 2,
        (long long)9 * HW4, (long long)64 * HW4, nullptr, nullptr, nullptr, nullptr);
    mean_part_k<<<dim3(256, 8), blk, 0, stream>>>(A, part, HW4 / 8);
    mean_fin_k<<<dim3(1), blk, 0, stream>>>(part, amean, 8, 1.f / HW4, 256);
    tchain_k<<<dim3(4), dim3(64), 0, stream>>>(amean, t1_w, t1_b, t2_w, t2_b, t3_w, t3_b, theta);

    //    lf conv -> AB, means, FC chain -> gamma/beta[4][32]
    conv16_k<0><<<dim3(128, 2, 4), blk, 0, stream>>>(haarA, wpack + 10 * 10240, A, 3, 256, 256, 2,
        (long long)3 * HW4, (long long)64 * HW4, nullptr, nullptr, nullptr, nullptr);
    mean_part_k<<<dim3(256, 8), blk, 0, stream>>>(A, part, HW4 / 8);
    mean_fin_k<<<dim3(1), blk, 0, stream>>>(part, am0, 8, 1.f / HW4, 256);
    fc_k<0><<<dim3(8), blk, 0, stream>>>(am0, fc1_w, fc1_b, am1, 64, 512);
    fc_k<0><<<dim3(8), blk, 0, stream>>>(am1, fc2_w, fc2_b, am2, 512, 512);
    fc_k<1><<<dim3(8), blk, 0, stream>>>(am2, fc3_w, fc3_b, am3, 512, 512);
    gb_k<<<dim3(4), dim3(64), 0, stream>>>(am3, g_w, g_b, be_w, be_b, gamma, beta);

    // 4. cdc packs (theta-folded, per batch)
    for (int b = 0; b < 4; ++b)
        pack_k<<<1, 64, 0, stream>>>(cdc_w, nullptr, theta + b, wpack + (12 + b) * 10240, 32, 32);

    // 5. heavy chain per batch (512x512, grid 4x128 = 512 blocks)
    const dim3 g512(512, 1, 1);
    for (int b = 0; b < 4; ++b) {
        const float* xb  = x + (size_t)b * 3 * HW;
        float* outE = out + (size_t)b * 3 * HW;
        float* outM = out + (size_t)4 * 3 * HW + (size_t)b * HW;

        conv16_k<0><<<g512, blk, 0, stream>>>(xb, wpack + 0 * 10240, A, 3, 512, 512, 4, 0, 0, nullptr, nullptr, nullptr, nullptr);
        conv16_k<0><<<g512, blk, 0, stream>>>(A,  wpack + 1 * 10240, Bb, 32, 512, 512, 4, 0, 0, nullptr, nullptr, nullptr, nullptr);
        conv16_k<0><<<g512, blk, 0, stream>>>(Bb, wpack + 2 * 10240, A, 32, 512, 512, 4, 0, 0, nullptr, nullptr, nullptr, nullptr);
        conv16_k<0><<<g512, blk, 0, stream>>>(A,  wpack + 3 * 10240, Bb, 32, 512, 512, 4, 0, 0, nullptr, nullptr, nullptr, nullptr);
        conv16_k<0><<<g512, blk, 0, stream>>>(Bb, wpack + 4 * 10240, A, 32, 512, 512, 4, 0, 0, nullptr, nullptr, nullptr, nullptr);
        // cdc (theta folded into center tap), A -> Bb = f_deco
        conv16_k<0><<<g512, blk, 0, stream>>>(A,  wpack + (12 + b) * 10240, Bb, 32, 512, 512, 4, 0, 0, nullptr, nullptr, nullptr, nullptr);
        // res: A = f_deco + gamma*(conv(f_deco)+res_b) + beta
        conv16_k<2><<<g512, blk, 0, stream>>>(Bb, wpack + 5 * 10240, A, 32, 512, 512, 4, 0, 0, gamma + 32 * b, beta + 32 * b, nullptr, nullptr);
        // d1
        conv16_k<0><<<g512, blk, 0, stream>>>(A,  wpack + 6 * 10240, Bb, 32, 512, 512, 4, 0, 0, nullptr, nullptr, nullptr, nullptr);
        // d2 + tanh + enhance
        conv16_k<3><<<g512, blk, 0, stream>>>(Bb, wpack + 7 * 10240, outE, 32, 512, 512, 4, 0, 0, nullptr, nullptr, xb, outM);
    }
}

// Round 4
// 853.113 us; speedup vs baseline: 8.8749x; 1.2882x over previous
//
#include <hip/hip_runtime.h>
#include <hip/hip_bf16.h>
#include <cmath>

#define TPB 256

typedef __attribute__((ext_vector_type(8))) short s16x8;
typedef __attribute__((ext_vector_type(4))) float f32x4;
typedef unsigned short ushortT;

static __device__ __forceinline__ short f2bf(float f) {
    union { __hip_bfloat16 h; short s; } u;
    u.h = __float2bfloat16(f);
    return u.s;
}
static __device__ __forceinline__ float bf2f(unsigned short u) {
    union { unsigned int i; float f; } v;
    v.i = ((unsigned int)u) << 16;
    return v.f;
}
static __device__ __forceinline__ unsigned int pack2(float a, float b) {
    return (unsigned int)(unsigned short)f2bf(a) | ((unsigned int)(unsigned short)f2bf(b) << 16);
}

#define COMP(vec,k) ((k)==0?(vec).x:((k)==1?(vec).y:((k)==2?(vec).z:(vec).w)))

// ---------------------------------------------------------------------------
// Weight pack body: OIHW fp32 -> per-lane MFMA A-fragments (bf16) + fp32 bias.
// shorts[((t*2+mt)*64+lane)*8+i] = w[co=cog*32+16mt+(lane&15)][ci=8*(lane>>4)+i][t]
// cdc fold: center tap -= theta * sum_taps  (== conv3x3 - theta*conv1x1(kdiff))
// bias fp32[32] at short-offset 9216; slot stride 10240 shorts.
// ---------------------------------------------------------------------------
static __device__ void pack_body(const float* w, const float* bias, const float* theta,
                                 short* dst, int CO, int CI, int cog, int l)
{
    const int l15 = l & 15, sl = l >> 4;
    for (int t = 0; t < 9; ++t) {
        for (int mt = 0; mt < 2; ++mt) {
            const int co = cog * 32 + 16 * mt + l15;
            s16x8 p;
            #pragma unroll
            for (int i = 0; i < 8; ++i) {
                const int ci = 8 * sl + i;
                float val = 0.f;
                if (co < CO && ci < CI) {
                    val = w[((size_t)co * CI + ci) * 9 + t];
                    if (theta && t == 4) {
                        float s = 0.f;
                        for (int tt = 0; tt < 9; ++tt) s += w[((size_t)co * CI + ci) * 9 + tt];
                        val -= theta[0] * s;
                    }
                }
                p[i] = f2bf(val);
            }
            *(s16x8*)(dst + ((size_t)(t * 2 + mt) * 64 + l) * 8) = p;
        }
    }
    if (l < 32) {
        const int co = cog * 32 + l;
        ((float*)(dst + 9216))[l] = (bias && co < CO) ? bias[co] : 0.f;
    }
}

// all static packs in one launch: 12 blocks of 64 threads
__global__ __launch_bounds__(64) void packall_k(
    const float* e1w, const float* e1b, const float* e2w, const float* e2b,
    const float* e3w, const float* e3b, const float* e4w, const float* e4b,
    const float* e5w, const float* e5b, const float* resw, const float* resb,
    const float* d1w, const float* d1b, const float* d2w, const float* d2b,
    const float* ctw, const float* ctb, const float* lfw, const float* lfb,
    short* wpack)
{
    const int s = blockIdx.x;
    const float *w, *b;
    int CO = 32, CI = 32, cog = 0;
    switch (s) {
        case 0: w = e1w; b = e1b; CI = 3; break;
        case 1: w = e2w; b = e2b; break;
        case 2: w = e3w; b = e3b; break;
        case 3: w = e4w; b = e4b; break;
        case 4: w = e5w; b = e5b; break;
        case 5: w = resw; b = resb; break;
        case 6: w = d1w; b = d1b; break;
        case 7: w = d2w; b = d2b; CO = 1; break;
        case 8: case 9: w = ctw; b = ctb; CO = 64; CI = 9; cog = s - 8; break;
        default: w = lfw; b = lfb; CO = 64; CI = 3; cog = s - 10; break;
    }
    pack_body(w, b, nullptr, wpack + (size_t)s * 10240, CO, CI, cog, threadIdx.x);
}

// cdc packs for all 4 batches (theta-folded)
__global__ __launch_bounds__(64) void packcdc_k(
    const float* cdcw, const float* theta, short* wpack)
{
    const int b = blockIdx.x;
    pack_body(cdcw, nullptr, theta + b, wpack + (size_t)(12 + b) * 10240, 32, 32, 0, threadIdx.x);
}

// ---------------------------------------------------------------------------
// zero halo rings of the two padded NHWC buffers (514x514x32 bf16) + mean raws
// uint-granular; per buffer 32832 uint tasks.
// ---------------------------------------------------------------------------
__global__ __launch_bounds__(TPB) void zero_k(
    unsigned int* A, unsigned int* B, float* meanraw)
{
    const int idx = blockIdx.x * TPB + threadIdx.x;
    if (idx < 512) meanraw[idx] = 0.f;
    if (idx >= 2 * 32832) return;
    unsigned int* P = (idx < 32832) ? A : B;
    const int r = idx % 32832;
    const int RSU = 514 * 16;  // row stride in uints
    int off;
    if (r < 8224)       off = r;                                         // top row
    else if (r < 16448) off = 513 * RSU + (r - 8224);                    // bottom row
    else if (r < 24640) { int u = r - 16448; off = (1 + (u >> 4)) * RSU + (u & 15); }             // left col
    else                { int u = r - 24640; off = (1 + (u >> 4)) * RSU + 513 * 16 + (u & 15); }  // right col
    P[off] = 0u;
}

// ---------------------------------------------------------------------------
// LDS-staged MFMA conv (fp32 NCHW input), used for enc1 / ct / lf.
// EPI: 0 = bias+relu -> padded NHWC bf16 out
//      4 = bias+relu -> atomic per-channel sum (no spatial output)
// ---------------------------------------------------------------------------
template<int EPI>
__global__ __launch_bounds__(TPB) void conv16_k(
    const float* __restrict__ in0, const short* __restrict__ wpack0,
    ushortT* __restrict__ outP, float* __restrict__ meanraw,
    int CI, int H, int W, int ntx, long long bstr_in)
{
    constexpr int RSX = 130;
    constexpr int ROWB = RSX * 64;
    __shared__ s16x8 lds_t[6 * RSX * 4];
    char* sb = (char*)lds_t;

    const int tid  = threadIdx.x;
    const int lane = tid & 63;
    const int wv   = tid >> 6;
    const float* in = in0 + (size_t)blockIdx.z * bstr_in;
    const int cog  = blockIdx.y;
    const short* wslot = wpack0 + (size_t)cog * 10240;
    const int tx = blockIdx.x % ntx, tyb = blockIdx.x / ntx;
    const int x0g = tx * 128, y0 = tyb * 4;
    const size_t HW = (size_t)H * W;

    s16x8 wf[9][2];
    #pragma unroll
    for (int t = 0; t < 9; ++t)
        #pragma unroll
        for (int mt = 0; mt < 2; ++mt)
            wf[t][mt] = *(const s16x8*)(wslot + ((size_t)(t * 2 + mt) * 64 + lane) * 8);

    for (int q = tid; q < 768; q += TPB) {
        const int xq = q & 31, o = (q >> 5) & 3, row = q >> 7;
        const int gy = y0 - 1 + row;
        const bool yok = (gy >= 0) && (gy < H);
        const float* gp = in + (size_t)gy * W + x0g + 4 * xq;
        float4 v[8];
        #pragma unroll
        for (int j = 0; j < 8; ++j) {
            const int ci = 8 * o + j;
            if (yok && ci < CI) v[j] = *(const float4*)(gp + (size_t)ci * HW);
            else                v[j] = make_float4(0.f, 0.f, 0.f, 0.f);
        }
        #pragma unroll
        for (int k = 0; k < 4; ++k) {
            const int lx = 1 + 4 * xq + k;
            const int vs = (lx + (lx >> 2)) & 3;
            s16x8 p;
            #pragma unroll
            for (int j = 0; j < 8; ++j) p[j] = f2bf(COMP(v[j], k));
            *(s16x8*)(sb + (row * RSX + lx) * 64 + ((o ^ vs) << 4)) = p;
        }
    }
    if (tid < 48) {
        const int side = tid & 1, o = (tid >> 1) & 3, row = tid >> 3;
        const int gy = y0 - 1 + row;
        const int lx = side ? 129 : 0;
        const int gx = x0g + (side ? 128 : -1);
        const bool ok = (gy >= 0) && (gy < H) && (gx >= 0) && (gx < W);
        s16x8 p;
        #pragma unroll
        for (int j = 0; j < 8; ++j) {
            const int ci = 8 * o + j;
            p[j] = f2bf((ok && ci < CI) ? in[(size_t)ci * HW + (size_t)gy * W + gx] : 0.f);
        }
        const int vs = (lx + (lx >> 2)) & 3;
        *(s16x8*)(sb + (row * RSX + lx) * 64 + ((o ^ vs) << 4)) = p;
    }
    __syncthreads();

    const int xw = 32 * wv;
    const int l15 = lane & 15, slot = lane >> 4;
    int roff[3][2];
    #pragma unroll
    for (int dx = 0; dx < 3; ++dx)
        #pragma unroll
        for (int nt = 0; nt < 2; ++nt) {
            const int lx = xw + 16 * nt + dx + l15;
            const int vs = (lx + (lx >> 2)) & 3;
            roff[dx][nt] = lx * 64 + ((slot ^ vs) << 4);
        }

    const float* bptr = (const float*)(wslot + 9216);
    float ps[2][4];
    if constexpr (EPI == 4) {
        #pragma unroll
        for (int mt = 0; mt < 2; ++mt)
            #pragma unroll
            for (int reg = 0; reg < 4; ++reg) ps[mt][reg] = 0.f;
    }

    for (int r2 = 0; r2 < 4; r2 += 2) {
        f32x4 acc[2][2][2];
        #pragma unroll
        for (int a = 0; a < 2; ++a)
            #pragma unroll
            for (int b = 0; b < 2; ++b)
                #pragma unroll
                for (int c = 0; c < 2; ++c)
                    #pragma unroll
                    for (int e = 0; e < 4; ++e) acc[a][b][c][e] = 0.f;

        #pragma unroll
        for (int dy = 0; dy < 3; ++dy) {
            const int rb0 = (r2 + dy) * ROWB;
            #pragma unroll
            for (int dx = 0; dx < 3; ++dx) {
                const int t = dy * 3 + dx;
                #pragma unroll
                for (int nt = 0; nt < 2; ++nt) {
                    const s16x8 b0 = *(const s16x8*)(sb + rb0 + roff[dx][nt]);
                    const s16x8 b1 = *(const s16x8*)(sb + rb0 + ROWB + roff[dx][nt]);
                    #pragma unroll
                    for (int mt = 0; mt < 2; ++mt) {
                        acc[0][mt][nt] = __builtin_amdgcn_mfma_f32_16x16x32_bf16(wf[t][mt], b0, acc[0][mt][nt], 0, 0, 0);
                        acc[1][mt][nt] = __builtin_amdgcn_mfma_f32_16x16x32_bf16(wf[t][mt], b1, acc[1][mt][nt], 0, 0, 0);
                    }
                }
            }
        }

        #pragma unroll
        for (int rr = 0; rr < 2; ++rr) {
            const int gy = y0 + r2 + rr;
            #pragma unroll
            for (int mt = 0; mt < 2; ++mt)
                #pragma unroll
                for (int nt = 0; nt < 2; ++nt) {
                    const int gx = x0g + xw + 16 * nt + l15;
                    if constexpr (EPI == 0) {
                        float v[4];
                        #pragma unroll
                        for (int reg = 0; reg < 4; ++reg)
                            v[reg] = fmaxf(acc[rr][mt][nt][reg] + bptr[16 * mt + 4 * slot + reg], 0.f);
                        uint2 pk = make_uint2(pack2(v[0], v[1]), pack2(v[2], v[3]));
                        *(uint2*)(outP + ((size_t)(gy + 1) * 514 + gx + 1) * 32 + 16 * mt + 4 * slot) = pk;
                    } else {
                        #pragma unroll
                        for (int reg = 0; reg < 4; ++reg)
                            ps[mt][reg] += fmaxf(acc[rr][mt][nt][reg] + bptr[16 * mt + 4 * slot + reg], 0.f);
                    }
                }
        }
    }

    if constexpr (EPI == 4) {
        #pragma unroll
        for (int mt = 0; mt < 2; ++mt)
            #pragma unroll
            for (int reg = 0; reg < 4; ++reg) {
                float s = ps[mt][reg];
                #pragma unroll
                for (int o = 1; o < 16; o <<= 1) s += __shfl_xor(s, o, 64);
                if (l15 == 0)
                    atomicAdd(&meanraw[blockIdx.z * 64 + cog * 32 + 16 * mt + 4 * slot + reg], s);
            }
    }
}

// ---------------------------------------------------------------------------
// Direct-global MFMA conv on padded NHWC bf16 (514x514x32), H=W=512.
// 256 thr = 4 waves; tile 128px x 4 rows x 32co. B-fragments loaded straight
// from global (16B/lane, aligned); no LDS, no barriers.
// EPI: 0 bias+relu->NHWC | 1 bias only->NHWC (unused) |
//      2 res: in + gamma[co]*(acc+bias)+beta[co] -> NHWC | 3 d2+tanh+enhance
// ---------------------------------------------------------------------------
template<int EPI>
__global__ __launch_bounds__(TPB) void dconv_k(
    const ushortT* __restrict__ inP, const short* __restrict__ wslot,
    ushortT* __restrict__ outP,
    const float* __restrict__ gamma, const float* __restrict__ beta,
    const float* __restrict__ xorig, float* __restrict__ outE, float* __restrict__ outM)
{
    const int tid = threadIdx.x, lane = tid & 63, wv = tid >> 6;
    const int bid = blockIdx.x;
    const int swz = (bid & 7) * 64 + (bid >> 3);      // XCD-contiguous y-tiles
    const int x0 = (swz & 3) * 128, y0 = (swz >> 2) * 4;
    const int l15 = lane & 15, slot = lane >> 4;
    const int xb = x0 + 32 * wv + l15;

    s16x8 wf[9][2];
    #pragma unroll
    for (int t = 0; t < 9; ++t)
        #pragma unroll
        for (int mt = 0; mt < 2; ++mt)
            wf[t][mt] = *(const s16x8*)(wslot + ((size_t)(t * 2 + mt) * 64 + lane) * 8);
    const float* bptr = (const float*)(wslot + 9216);

    #pragma unroll 1
    for (int r = 0; r < 4; ++r) {
        const int gy = y0 + r;
        f32x4 acc[2][2];
        #pragma unroll
        for (int mt = 0; mt < 2; ++mt)
            #pragma unroll
            for (int nt = 0; nt < 2; ++nt)
                #pragma unroll
                for (int e = 0; e < 4; ++e) acc[mt][nt][e] = 0.f;

        s16x8 bv[3][3][2];
        #pragma unroll
        for (int dy = 0; dy < 3; ++dy)
            #pragma unroll
            for (int dx = 0; dx < 3; ++dx)
                #pragma unroll
                for (int nt = 0; nt < 2; ++nt)
                    bv[dy][dx][nt] = *(const s16x8*)(inP + ((size_t)(gy + dy) * 514 + xb + 16 * nt + dx) * 32 + 8 * slot);

        #pragma unroll
        for (int dy = 0; dy < 3; ++dy)
            #pragma unroll
            for (int dx = 0; dx < 3; ++dx)
                #pragma unroll
                for (int nt = 0; nt < 2; ++nt)
                    #pragma unroll
                    for (int mt = 0; mt < 2; ++mt)
                        acc[mt][nt] = __builtin_amdgcn_mfma_f32_16x16x32_bf16(wf[dy * 3 + dx][mt], bv[dy][dx][nt], acc[mt][nt], 0, 0, 0);

        if constexpr (EPI == 3) {
            if (slot == 0) {
                const float b0 = bptr[0];
                #pragma unroll
                for (int nt = 0; nt < 2; ++nt) {
                    const int gx = xb + 16 * nt;
                    const float om = tanhf(acc[0][nt][0] + b0);
                    outM[(size_t)gy * 512 + gx] = om;
                    #pragma unroll
                    for (int c = 0; c < 3; ++c) {
                        const size_t xi = ((size_t)c * 512 + gy) * 512 + gx;
                        const float xv = xorig[xi];
                        outE[xi] = xv + om * (xv * xv - xv);
                    }
                }
            }
        } else {
            #pragma unroll
            for (int mt = 0; mt < 2; ++mt)
                #pragma unroll
                for (int nt = 0; nt < 2; ++nt) {
                    const int gx = xb + 16 * nt;
                    const size_t off = ((size_t)(gy + 1) * 514 + gx + 1) * 32 + 16 * mt + 4 * slot;
                    float v[4];
                    #pragma unroll
                    for (int reg = 0; reg < 4; ++reg)
                        v[reg] = acc[mt][nt][reg] + bptr[16 * mt + 4 * slot + reg];
                    if constexpr (EPI == 0) {
                        #pragma unroll
                        for (int reg = 0; reg < 4; ++reg) v[reg] = fmaxf(v[reg], 0.f);
                    } else if constexpr (EPI == 2) {
                        const uint2 din = *(const uint2*)(inP + off);
                        const float d0 = bf2f((unsigned short)(din.x & 0xffff));
                        const float d1 = bf2f((unsigned short)(din.x >> 16));
                        const float d2v = bf2f((unsigned short)(din.y & 0xffff));
                        const float d3 = bf2f((unsigned short)(din.y >> 16));
                        const int cb = 16 * mt + 4 * slot;
                        v[0] = d0 + gamma[cb + 0] * v[0] + beta[cb + 0];
                        v[1] = d1 + gamma[cb + 1] * v[1] + beta[cb + 1];
                        v[2] = d2v + gamma[cb + 2] * v[2] + beta[cb + 2];
                        v[3] = d3 + gamma[cb + 3] * v[3] + beta[cb + 3];
                    }
                    *(uint2*)(outP + off) = make_uint2(pack2(v[0], v[1]), pack2(v[2], v[3]));
                }
        }
    }
}

// ---------------------------------------------------------------------------
// Haar DWT (all 4 batches)
// ---------------------------------------------------------------------------
__global__ __launch_bounds__(TPB) void dwt_k(
    const float* __restrict__ x, float* __restrict__ haarA, float* __restrict__ hf)
{
    const int idx = blockIdx.x * TPB + threadIdx.x;
    if (idx >= 4 * 256 * 256) return;
    const int xo = idx & 255;
    const int yo = (idx >> 8) & 255;
    const int b  = idx >> 16;
    #pragma unroll
    for (int c = 0; c < 3; ++c) {
        const float* p = x + (((size_t)b * 3 + c) * 512 + 2 * yo) * 512 + 2 * xo;
        const float a = p[0], bb = p[1], cc = p[512], d = p[513];
        haarA[(((size_t)b * 3 + c) * 256 + yo) * 256 + xo] = 0.5f * (a + bb + cc + d);
        hf[(((size_t)b * 9 + 0 + c) * 256 + yo) * 256 + xo] = 0.5f * (a + bb - cc - d);
        hf[(((size_t)b * 9 + 3 + c) * 256 + yo) * 256 + xo] = 0.5f * (a - bb + cc - d);
        hf[(((size_t)b * 9 + 6 + c) * 256 + yo) * 256 + xo] = 0.5f * (a - bb - cc + d);
    }
}

// scale raw channel sums -> means (512 entries: amean[4][64] | am0[4][64])
__global__ __launch_bounds__(TPB) void scale_k(
    const float* __restrict__ raw, float* __restrict__ out)
{
    const int i = blockIdx.x * TPB + threadIdx.x;
    if (i < 512) out[i] = raw[i] * (1.f / 65536.f);
}

// ---------------------------------------------------------------------------
// t1->t2->t3 chain, blockIdx.x = b
// ---------------------------------------------------------------------------
__global__ __launch_bounds__(64) void tchain_k(
    const float* __restrict__ amean,
    const float* __restrict__ t1w, const float* __restrict__ t1b,
    const float* __restrict__ t2w, const float* __restrict__ t2b,
    const float* __restrict__ t3w, const float* __restrict__ t3b,
    float* __restrict__ theta)
{
    const int b = blockIdx.x;
    const float* am = amean + b * 64;
    __shared__ float a0[64], a1[64], a2[64];
    const int co = threadIdx.x;
    a0[co] = am[co];
    __syncthreads();
    float s = t1b[co];
    #pragma unroll 8
    for (int ci = 0; ci < 64; ++ci) s = fmaf(t1w[co * 64 + ci], a0[ci], s);
    a1[co] = fmaxf(s, 0.f);
    __syncthreads();
    s = t2b[co];
    #pragma unroll 8
    for (int ci = 0; ci < 64; ++ci) s = fmaf(t2w[co * 64 + ci], a1[ci], s);
    a2[co] = fmaxf(s, 0.f);
    __syncthreads();
    if (co == 0) {
        float v = t3b[0];
        for (int ci = 0; ci < 64; ++ci) v = fmaf(t3w[ci], a2[ci], v);
        theta[b] = 1.f / (1.f + expf(-v));
    }
}

// ---------------------------------------------------------------------------
// wave-per-output FC: out[b*N+co] = act(w[co,:]@in[b,:] + bias[co])
// grid = N (4 waves/block -> 4 outputs/block over 4N total). ACT 0 relu,
// 1 sigmoid, 2 tanh.
// ---------------------------------------------------------------------------
template<int ACT>
__global__ __launch_bounds__(TPB) void fcw_k(
    const float* __restrict__ in, const float* __restrict__ w,
    const float* __restrict__ bias, float* __restrict__ out, int K, int N)
{
    const int lane = threadIdx.x & 63, wv = threadIdx.x >> 6;
    const int idx = blockIdx.x * 4 + wv;
    if (idx >= 4 * N) return;
    const int b = idx / N, co = idx % N;
    float s = 0.f;
    for (int k = lane * 4; k < K; k += 256) {
        const float4 wv4 = *(const float4*)(w + (size_t)co * K + k);
        const float4 iv  = *(const float4*)(in + (size_t)b * K + k);
        s += wv4.x * iv.x + wv4.y * iv.y + wv4.z * iv.z + wv4.w * iv.w;
    }
    #pragma unroll
    for (int o = 32; o > 0; o >>= 1) s += __shfl_xor(s, o, 64);
    if (lane == 0) {
        s += bias[co];
        if (ACT == 0) s = fmaxf(s, 0.f);
        else if (ACT == 1) s = 1.f / (1.f + expf(-s));
        else s = tanhf(s);
        out[(size_t)b * N + co] = s;
    }
}

// ---------------------------------------------------------------------------
extern "C" void kernel_launch(void* const* d_in, const int* in_sizes, int n_in,
                              void* d_out, int out_size, void* d_ws, size_t ws_size,
                              hipStream_t stream)
{
    const float* x      = (const float*)d_in[0];
    const float* cdc_w  = (const float*)d_in[11];
    const float* t1_w   = (const float*)d_in[14];
    const float* t1_b   = (const float*)d_in[15];
    const float* t2_w   = (const float*)d_in[16];
    const float* t2_b   = (const float*)d_in[17];
    const float* t3_w   = (const float*)d_in[18];
    const float* t3_b   = (const float*)d_in[19];
    const float* fc1_w  = (const float*)d_in[22];
    const float* fc1_b  = (const float*)d_in[23];
    const float* fc2_w  = (const float*)d_in[24];
    const float* fc2_b  = (const float*)d_in[25];
    const float* fc3_w  = (const float*)d_in[26];
    const float* fc3_b  = (const float*)d_in[27];
    const float* g_w    = (const float*)d_in[28];
    const float* g_b    = (const float*)d_in[29];
    const float* be_w   = (const float*)d_in[30];
    const float* be_b   = (const float*)d_in[31];

    float* out = (float*)d_out;
    const int HW = 512 * 512;

    // workspace layout
    ushortT* A_p = (ushortT*)d_ws;                 // 514*514*32 bf16 = 16.9 MB
    ushortT* B_p = A_p + 8454272;
    float* haarA  = (float*)(B_p + 8454272);       // (4,3,256,256)
    float* hf     = haarA + 786432;                // (4,9,256,256)
    float* meanraw = hf + 2359296;                 // 512: ct sums | lf sums
    float* meansc  = meanraw + 512;                // 512: amean | am0
    float* am1    = meansc + 512;                  // 2048
    float* am2    = am1 + 2048;
    float* am3    = am2 + 2048;
    float* theta  = am3 + 2048;                    // 4
    float* gamma  = theta + 4;                     // 128 [4][32]
    float* beta   = gamma + 128;                   // 128
    short* wpack  = (short*)(beta + 128);          // 16 slots x 10240 shorts
    const size_t need_bytes = (size_t)((char*)(wpack + 16 * 10240) - (char*)d_ws);
    if (ws_size < need_bytes) return;

    const dim3 blk(TPB);

    // 1. zero halo rings + mean accumulators; DWT; static weight packs
    zero_k<<<dim3(257), blk, 0, stream>>>((unsigned int*)A_p, (unsigned int*)B_p, meanraw);
    dwt_k<<<dim3((4 * 256 * 256 + TPB - 1) / TPB), blk, 0, stream>>>(x, haarA, hf);
    packall_k<<<dim3(12), dim3(64), 0, stream>>>(
        (const float*)d_in[1], (const float*)d_in[2], (const float*)d_in[3], (const float*)d_in[4],
        (const float*)d_in[5], (const float*)d_in[6], (const float*)d_in[7], (const float*)d_in[8],
        (const float*)d_in[9], (const float*)d_in[10], (const float*)d_in[32], (const float*)d_in[33],
        (const float*)d_in[34], (const float*)d_in[35], (const float*)d_in[36], (const float*)d_in[37],
        (const float*)d_in[12], (const float*)d_in[13], (const float*)d_in[20], (const float*)d_in[21],
        wpack);

    // 2. phase A: ct/lf convs fused into channel means (batched over z)
    conv16_k<4><<<dim3(128, 2, 4), blk, 0, stream>>>(hf, wpack + 8 * 10240, nullptr, meanraw,
        9, 256, 256, 2, (long long)9 * 65536);
    conv16_k<4><<<dim3(128, 2, 4), blk, 0, stream>>>(haarA, wpack + 10 * 10240, nullptr, meanraw + 256,
        3, 256, 256, 2, (long long)3 * 65536);
    scale_k<<<dim3(2), blk, 0, stream>>>(meanraw, meansc);
    tchain_k<<<dim3(4), dim3(64), 0, stream>>>(meansc, t1_w, t1_b, t2_w, t2_b, t3_w, t3_b, theta);
    fcw_k<0><<<dim3(512), blk, 0, stream>>>(meansc + 256, fc1_w, fc1_b, am1, 64, 512);
    fcw_k<0><<<dim3(512), blk, 0, stream>>>(am1, fc2_w, fc2_b, am2, 512, 512);
    fcw_k<1><<<dim3(512), blk, 0, stream>>>(am2, fc3_w, fc3_b, am3, 512, 512);
    fcw_k<1><<<dim3(32), blk, 0, stream>>>(am3, g_w, g_b, gamma, 512, 32);
    fcw_k<2><<<dim3(32), blk, 0, stream>>>(am3, be_w, be_b, beta, 512, 32);
    packcdc_k<<<dim3(4), dim3(64), 0, stream>>>(cdc_w, theta, wpack);

    // 3. heavy chain per batch (NHWC bf16 padded ping-pong, direct-global convs)
    const dim3 g512(512);
    for (int b = 0; b < 4; ++b) {
        const float* xb = x + (size_t)b * 3 * HW;
        float* outE = out + (size_t)b * 3 * HW;
        float* outM = out + (size_t)4 * 3 * HW + (size_t)b * HW;

        // enc1: fp32 NCHW -> NHWC bf16 (LDS-staged kernel)
        conv16_k<0><<<dim3(512, 1, 1), blk, 0, stream>>>(xb, wpack, A_p, nullptr, 3, 512, 512, 4, 0);
        // enc2..enc5
        dconv_k<0><<<g512, blk, 0, stream>>>(A_p, wpack + 1 * 10240, B_p, nullptr, nullptr, nullptr, nullptr, nullptr);
        dconv_k<0><<<g512, blk, 0, stream>>>(B_p, wpack + 2 * 10240, A_p, nullptr, nullptr, nullptr, nullptr, nullptr);
        dconv_k<0><<<g512, blk, 0, stream>>>(A_p, wpack + 3 * 10240, B_p, nullptr, nullptr, nullptr, nullptr, nullptr);
        dconv_k<0><<<g512, blk, 0, stream>>>(B_p, wpack + 4 * 10240, A_p, nullptr, nullptr, nullptr, nullptr, nullptr);
        // cdc (theta folded): A -> B = f_deco
        dconv_k<0><<<g512, blk, 0, stream>>>(A_p, wpack + (size_t)(12 + b) * 10240, B_p, nullptr, nullptr, nullptr, nullptr, nullptr);
        // res: B -> A
        dconv_k<2><<<g512, blk, 0, stream>>>(B_p, wpack + 5 * 10240, A_p, gamma + 32 * b, beta + 32 * b, nullptr, nullptr, nullptr);
        // d1: A -> B
        dconv_k<0><<<g512, blk, 0, stream>>>(A_p, wpack + 6 * 10240, B_p, nullptr, nullptr, nullptr, nullptr, nullptr);
        // d2 + tanh + enhance -> outputs
        dconv_k<3><<<g512, blk, 0, stream>>>(B_p, wpack + 7 * 10240, nullptr, nullptr, nullptr, xb, outE, outM);
    }
}

// Round 5
// 622.827 us; speedup vs baseline: 12.1564x; 1.3697x over previous
//
#include <hip/hip_runtime.h>
#include <hip/hip_bf16.h>
#include <cmath>

#define TPB 256

typedef __attribute__((ext_vector_type(8))) short s16x8;
typedef __attribute__((ext_vector_type(4))) float f32x4;
typedef unsigned short ushortT;

constexpr long long PSTR = 8454272;   // 514*514*32 ushorts per padded image
constexpr int HW = 512 * 512;

static __device__ __forceinline__ short f2bf(float f) {
    union { __hip_bfloat16 h; short s; } u;
    u.h = __float2bfloat16(f);
    return u.s;
}
static __device__ __forceinline__ float bf2f(unsigned short u) {
    union { unsigned int i; float f; } v;
    v.i = ((unsigned int)u) << 16;
    return v.f;
}
static __device__ __forceinline__ unsigned int pack2(float a, float b) {
    return (unsigned int)(unsigned short)f2bf(a) | ((unsigned int)(unsigned short)f2bf(b) << 16);
}

#define COMP(vec,k) ((k)==0?(vec).x:((k)==1?(vec).y:((k)==2?(vec).z:(vec).w)))

// ---------------------------------------------------------------------------
// Weight pack body (see round 3). slot stride 10240 shorts; bias fp32 @9216.
// ---------------------------------------------------------------------------
static __device__ void pack_body(const float* w, const float* bias, const float* theta,
                                 short* dst, int CO, int CI, int cog, int l)
{
    const int l15 = l & 15, sl = l >> 4;
    for (int t = 0; t < 9; ++t) {
        for (int mt = 0; mt < 2; ++mt) {
            const int co = cog * 32 + 16 * mt + l15;
            s16x8 p;
            #pragma unroll
            for (int i = 0; i < 8; ++i) {
                const int ci = 8 * sl + i;
                float val = 0.f;
                if (co < CO && ci < CI) {
                    val = w[((size_t)co * CI + ci) * 9 + t];
                    if (theta && t == 4) {
                        float s = 0.f;
                        for (int tt = 0; tt < 9; ++tt) s += w[((size_t)co * CI + ci) * 9 + tt];
                        val -= theta[0] * s;
                    }
                }
                p[i] = f2bf(val);
            }
            *(s16x8*)(dst + ((size_t)(t * 2 + mt) * 64 + l) * 8) = p;
        }
    }
    if (l < 32) {
        const int co = cog * 32 + l;
        ((float*)(dst + 9216))[l] = (bias && co < CO) ? bias[co] : 0.f;
    }
}

__global__ __launch_bounds__(64) void packall_k(
    const float* e1w, const float* e1b, const float* e2w, const float* e2b,
    const float* e3w, const float* e3b, const float* e4w, const float* e4b,
    const float* e5w, const float* e5b, const float* resw, const float* resb,
    const float* d1w, const float* d1b, const float* d2w, const float* d2b,
    const float* ctw, const float* ctb, const float* lfw, const float* lfb,
    short* wpack)
{
    const int s = blockIdx.x;
    const float *w, *b;
    int CO = 32, CI = 32, cog = 0;
    switch (s) {
        case 0: w = e1w; b = e1b; CI = 3; break;
        case 1: w = e2w; b = e2b; break;
        case 2: w = e3w; b = e3b; break;
        case 3: w = e4w; b = e4b; break;
        case 4: w = e5w; b = e5b; break;
        case 5: w = resw; b = resb; break;
        case 6: w = d1w; b = d1b; break;
        case 7: w = d2w; b = d2b; CO = 1; break;
        case 8: case 9: w = ctw; b = ctb; CO = 64; CI = 9; cog = s - 8; break;
        default: w = lfw; b = lfb; CO = 64; CI = 3; cog = s - 10; break;
    }
    pack_body(w, b, nullptr, wpack + (size_t)s * 10240, CO, CI, cog, threadIdx.x);
}

__global__ __launch_bounds__(64) void packcdc_k(
    const float* cdcw, const float* theta, short* wpack)
{
    const int b = blockIdx.x;
    pack_body(cdcw, nullptr, theta + b, wpack + (size_t)(12 + b) * 10240, 32, 32, 0, threadIdx.x);
}

// ---------------------------------------------------------------------------
// zero halo rings of 4 padded NHWC buffers (A2 z0/z1, B2 z0/z1)
// per buffer 32832 uint tasks.
// ---------------------------------------------------------------------------
__global__ __launch_bounds__(TPB) void zero_k(unsigned int* A2u, unsigned int* B2u)
{
    const int idx = blockIdx.x * TPB + threadIdx.x;
    if (idx >= 4 * 32832) return;
    const int q = idx / 32832, r = idx % 32832;
    unsigned int* P = (q < 2 ? A2u : B2u) + (size_t)(q & 1) * 4227136;
    const int RSU = 514 * 16;
    int off;
    if (r < 8224)       off = r;
    else if (r < 16448) off = 513 * RSU + (r - 8224);
    else if (r < 24640) { int u = r - 16448; off = (1 + (u >> 4)) * RSU + (u & 15); }
    else                { int u = r - 24640; off = (1 + (u >> 4)) * RSU + 513 * 16 + (u & 15); }
    P[off] = 0u;
}

// ---------------------------------------------------------------------------
// LDS-staged MFMA conv (fp32 NCHW input): enc1 (EPI=0) / ct,lf (EPI=4).
// EPI 0: bias+relu -> padded NHWC bf16 (outP + z*bstr_outP)
// EPI 4: bias+relu -> per-block 32-channel partial sums (deterministic)
// ---------------------------------------------------------------------------
template<int EPI>
__global__ __launch_bounds__(TPB) void conv16_k(
    const float* __restrict__ in0, const short* __restrict__ wpack0,
    ushortT* __restrict__ outP0, long long bstr_outP, float* __restrict__ part,
    int CI, int H, int W, int ntx, long long bstr_in)
{
    constexpr int RSX = 130;
    constexpr int ROWB = RSX * 64;
    __shared__ s16x8 lds_t[6 * RSX * 4];
    __shared__ float s_red[4][32];
    char* sb = (char*)lds_t;

    const int tid  = threadIdx.x;
    const int lane = tid & 63;
    const int wv   = tid >> 6;
    const float* in = in0 + (size_t)blockIdx.z * bstr_in;
    const int cog  = blockIdx.y;
    const short* wslot = wpack0 + (size_t)cog * 10240;
    const int tx = blockIdx.x % ntx, tyb = blockIdx.x / ntx;
    const int x0g = tx * 128, y0 = tyb * 4;
    const size_t HWl = (size_t)H * W;

    s16x8 wf[9][2];
    #pragma unroll
    for (int t = 0; t < 9; ++t)
        #pragma unroll
        for (int mt = 0; mt < 2; ++mt)
            wf[t][mt] = *(const s16x8*)(wslot + ((size_t)(t * 2 + mt) * 64 + lane) * 8);

    for (int q = tid; q < 768; q += TPB) {
        const int xq = q & 31, o = (q >> 5) & 3, row = q >> 7;
        const int gy = y0 - 1 + row;
        const bool yok = (gy >= 0) && (gy < H);
        const float* gp = in + (size_t)gy * W + x0g + 4 * xq;
        float4 v[8];
        #pragma unroll
        for (int j = 0; j < 8; ++j) {
            const int ci = 8 * o + j;
            if (yok && ci < CI) v[j] = *(const float4*)(gp + (size_t)ci * HWl);
            else                v[j] = make_float4(0.f, 0.f, 0.f, 0.f);
        }
        #pragma unroll
        for (int k = 0; k < 4; ++k) {
            const int lx = 1 + 4 * xq + k;
            const int vs = (lx + (lx >> 2)) & 3;
            s16x8 p;
            #pragma unroll
            for (int j = 0; j < 8; ++j) p[j] = f2bf(COMP(v[j], k));
            *(s16x8*)(sb + (row * RSX + lx) * 64 + ((o ^ vs) << 4)) = p;
        }
    }
    if (tid < 48) {
        const int side = tid & 1, o = (tid >> 1) & 3, row = tid >> 3;
        const int gy = y0 - 1 + row;
        const int lx = side ? 129 : 0;
        const int gx = x0g + (side ? 128 : -1);
        const bool ok = (gy >= 0) && (gy < H) && (gx >= 0) && (gx < W);
        s16x8 p;
        #pragma unroll
        for (int j = 0; j < 8; ++j) {
            const int ci = 8 * o + j;
            p[j] = f2bf((ok && ci < CI) ? in[(size_t)ci * HWl + (size_t)gy * W + gx] : 0.f);
        }
        const int vs = (lx + (lx >> 2)) & 3;
        *(s16x8*)(sb + (row * RSX + lx) * 64 + ((o ^ vs) << 4)) = p;
    }
    __syncthreads();

    const int xw = 32 * wv;
    const int l15 = lane & 15, slot = lane >> 4;
    int roff[3][2];
    #pragma unroll
    for (int dx = 0; dx < 3; ++dx)
        #pragma unroll
        for (int nt = 0; nt < 2; ++nt) {
            const int lx = xw + 16 * nt + dx + l15;
            const int vs = (lx + (lx >> 2)) & 3;
            roff[dx][nt] = lx * 64 + ((slot ^ vs) << 4);
        }

    const float* bptr = (const float*)(wslot + 9216);
    float ps[2][4];
    #pragma unroll
    for (int mt = 0; mt < 2; ++mt)
        #pragma unroll
        for (int reg = 0; reg < 4; ++reg) ps[mt][reg] = 0.f;

    for (int r2 = 0; r2 < 4; r2 += 2) {
        f32x4 acc[2][2][2];
        #pragma unroll
        for (int a = 0; a < 2; ++a)
            #pragma unroll
            for (int b = 0; b < 2; ++b)
                #pragma unroll
                for (int c = 0; c < 2; ++c)
                    #pragma unroll
                    for (int e = 0; e < 4; ++e) acc[a][b][c][e] = 0.f;

        #pragma unroll
        for (int dy = 0; dy < 3; ++dy) {
            const int rb0 = (r2 + dy) * ROWB;
            #pragma unroll
            for (int dx = 0; dx < 3; ++dx) {
                const int t = dy * 3 + dx;
                #pragma unroll
                for (int nt = 0; nt < 2; ++nt) {
                    const s16x8 b0 = *(const s16x8*)(sb + rb0 + roff[dx][nt]);
                    const s16x8 b1 = *(const s16x8*)(sb + rb0 + ROWB + roff[dx][nt]);
                    #pragma unroll
                    for (int mt = 0; mt < 2; ++mt) {
                        acc[0][mt][nt] = __builtin_amdgcn_mfma_f32_16x16x32_bf16(wf[t][mt], b0, acc[0][mt][nt], 0, 0, 0);
                        acc[1][mt][nt] = __builtin_amdgcn_mfma_f32_16x16x32_bf16(wf[t][mt], b1, acc[1][mt][nt], 0, 0, 0);
                    }
                }
            }
        }

        #pragma unroll
        for (int rr = 0; rr < 2; ++rr) {
            const int gy = y0 + r2 + rr;
            #pragma unroll
            for (int mt = 0; mt < 2; ++mt)
                #pragma unroll
                for (int nt = 0; nt < 2; ++nt) {
                    const int gx = x0g + xw + 16 * nt + l15;
                    if constexpr (EPI == 0) {
                        ushortT* outP = outP0 + (size_t)blockIdx.z * bstr_outP;
                        float v[4];
                        #pragma unroll
                        for (int reg = 0; reg < 4; ++reg)
                            v[reg] = fmaxf(acc[rr][mt][nt][reg] + bptr[16 * mt + 4 * slot + reg], 0.f);
                        *(uint2*)(outP + ((size_t)(gy + 1) * 514 + gx + 1) * 32 + 16 * mt + 4 * slot) =
                            make_uint2(pack2(v[0], v[1]), pack2(v[2], v[3]));
                    } else {
                        #pragma unroll
                        for (int reg = 0; reg < 4; ++reg)
                            ps[mt][reg] += fmaxf(acc[rr][mt][nt][reg] + bptr[16 * mt + 4 * slot + reg], 0.f);
                    }
                }
        }
    }

    if constexpr (EPI == 4) {
        // 16-lane butterfly: all lanes of each slot-group hold the group sum
        #pragma unroll
        for (int mt = 0; mt < 2; ++mt)
            #pragma unroll
            for (int reg = 0; reg < 4; ++reg) {
                #pragma unroll
                for (int o = 1; o < 16; o <<= 1)
                    ps[mt][reg] += __shfl_xor(ps[mt][reg], o, 64);
            }
        // static-indexed scatter: lane l15 = 4*mt+reg writes its value
        #pragma unroll
        for (int mt = 0; mt < 2; ++mt)
            #pragma unroll
            for (int reg = 0; reg < 4; ++reg)
                if (l15 == mt * 4 + reg)
                    s_red[wv][16 * mt + 4 * slot + reg] = ps[mt][reg];
        __syncthreads();
        if (tid < 32) {
            const float s = s_red[0][tid] + s_red[1][tid] + s_red[2][tid] + s_red[3][tid];
            part[(((size_t)blockIdx.z * gridDim.y + blockIdx.y) * gridDim.x + blockIdx.x) * 32 + tid] = s;
        }
    }
}

// ---------------------------------------------------------------------------
// Direct-global MFMA conv on padded NHWC bf16, z-batched (z = blockIdx.z).
// EPI: 0 bias+relu | 2 res: in + gamma[z,co]*(acc+bias)+beta[z,co] | 3 d2+enhance
// ---------------------------------------------------------------------------
template<int EPI>
__global__ __launch_bounds__(TPB) void dconv_k(
    const ushortT* __restrict__ inP0, const short* __restrict__ wbase, int wstr,
    ushortT* __restrict__ outP0,
    const float* __restrict__ gamma0, const float* __restrict__ beta0,
    const float* __restrict__ xorig0, float* __restrict__ outE0, float* __restrict__ outM0)
{
    const int z = blockIdx.z;
    const ushortT* inP = inP0 + (size_t)z * PSTR;
    const short* wslot = wbase + (size_t)z * wstr;

    const int tid = threadIdx.x, lane = tid & 63, wv = tid >> 6;
    const int bid = blockIdx.x;
    const int swz = (bid & 7) * 64 + (bid >> 3);
    const int x0 = (swz & 3) * 128, y0 = (swz >> 2) * 4;
    const int l15 = lane & 15, slot = lane >> 4;
    const int xb = x0 + 32 * wv + l15;

    s16x8 wf[9][2];
    #pragma unroll
    for (int t = 0; t < 9; ++t)
        #pragma unroll
        for (int mt = 0; mt < 2; ++mt)
            wf[t][mt] = *(const s16x8*)(wslot + ((size_t)(t * 2 + mt) * 64 + lane) * 8);
    const float* bptr = (const float*)(wslot + 9216);

    #pragma unroll 1
    for (int r = 0; r < 4; ++r) {
        const int gy = y0 + r;
        f32x4 acc[2][2];
        #pragma unroll
        for (int mt = 0; mt < 2; ++mt)
            #pragma unroll
            for (int nt = 0; nt < 2; ++nt)
                #pragma unroll
                for (int e = 0; e < 4; ++e) acc[mt][nt][e] = 0.f;

        s16x8 bv[3][3][2];
        #pragma unroll
        for (int dy = 0; dy < 3; ++dy)
            #pragma unroll
            for (int dx = 0; dx < 3; ++dx)
                #pragma unroll
                for (int nt = 0; nt < 2; ++nt)
                    bv[dy][dx][nt] = *(const s16x8*)(inP + ((size_t)(gy + dy) * 514 + xb + 16 * nt + dx) * 32 + 8 * slot);

        #pragma unroll
        for (int dy = 0; dy < 3; ++dy)
            #pragma unroll
            for (int dx = 0; dx < 3; ++dx)
                #pragma unroll
                for (int nt = 0; nt < 2; ++nt)
                    #pragma unroll
                    for (int mt = 0; mt < 2; ++mt)
                        acc[mt][nt] = __builtin_amdgcn_mfma_f32_16x16x32_bf16(wf[dy * 3 + dx][mt], bv[dy][dx][nt], acc[mt][nt], 0, 0, 0);

        if constexpr (EPI == 3) {
            if (slot == 0) {
                const float* xorig = xorig0 + (size_t)z * 3 * HW;
                float* outE = outE0 + (size_t)z * 3 * HW;
                float* outM = outM0 + (size_t)z * HW;
                const float b0 = bptr[0];
                #pragma unroll
                for (int nt = 0; nt < 2; ++nt) {
                    const int gx = xb + 16 * nt;
                    const float om = tanhf(acc[0][nt][0] + b0);
                    outM[(size_t)gy * 512 + gx] = om;
                    #pragma unroll
                    for (int c = 0; c < 3; ++c) {
                        const size_t xi = ((size_t)c * 512 + gy) * 512 + gx;
                        const float xv = xorig[xi];
                        outE[xi] = xv + om * (xv * xv - xv);
                    }
                }
            }
        } else {
            ushortT* outP = outP0 + (size_t)z * PSTR;
            #pragma unroll
            for (int mt = 0; mt < 2; ++mt)
                #pragma unroll
                for (int nt = 0; nt < 2; ++nt) {
                    const int gx = xb + 16 * nt;
                    const size_t off = ((size_t)(gy + 1) * 514 + gx + 1) * 32 + 16 * mt + 4 * slot;
                    float v[4];
                    #pragma unroll
                    for (int reg = 0; reg < 4; ++reg)
                        v[reg] = acc[mt][nt][reg] + bptr[16 * mt + 4 * slot + reg];
                    if constexpr (EPI == 0) {
                        #pragma unroll
                        for (int reg = 0; reg < 4; ++reg) v[reg] = fmaxf(v[reg], 0.f);
                    } else if constexpr (EPI == 2) {
                        const float* gamma = gamma0 + 32 * z;
                        const float* beta  = beta0 + 32 * z;
                        const uint2 din = *(const uint2*)(inP + off);
                        const int cb = 16 * mt + 4 * slot;
                        v[0] = bf2f((unsigned short)(din.x & 0xffff)) + gamma[cb + 0] * v[0] + beta[cb + 0];
                        v[1] = bf2f((unsigned short)(din.x >> 16))    + gamma[cb + 1] * v[1] + beta[cb + 1];
                        v[2] = bf2f((unsigned short)(din.y & 0xffff)) + gamma[cb + 2] * v[2] + beta[cb + 2];
                        v[3] = bf2f((unsigned short)(din.y >> 16))    + gamma[cb + 3] * v[3] + beta[cb + 3];
                    }
                    *(uint2*)(outP + off) = make_uint2(pack2(v[0], v[1]), pack2(v[2], v[3]));
                }
        }
    }
}

// ---------------------------------------------------------------------------
// Haar DWT (all 4 batches)
// ---------------------------------------------------------------------------
__global__ __launch_bounds__(TPB) void dwt_k(
    const float* __restrict__ x, float* __restrict__ haarA, float* __restrict__ hf)
{
    const int idx = blockIdx.x * TPB + threadIdx.x;
    if (idx >= 4 * 256 * 256) return;
    const int xo = idx & 255;
    const int yo = (idx >> 8) & 255;
    const int b  = idx >> 16;
    #pragma unroll
    for (int c = 0; c < 3; ++c) {
        const float* p = x + (((size_t)b * 3 + c) * 512 + 2 * yo) * 512 + 2 * xo;
        const float a = p[0], bb = p[1], cc = p[512], d = p[513];
        haarA[(((size_t)b * 3 + c) * 256 + yo) * 256 + xo] = 0.5f * (a + bb + cc + d);
        hf[(((size_t)b * 9 + 0 + c) * 256 + yo) * 256 + xo] = 0.5f * (a + bb - cc - d);
        hf[(((size_t)b * 9 + 3 + c) * 256 + yo) * 256 + xo] = 0.5f * (a - bb + cc - d);
        hf[(((size_t)b * 9 + 6 + c) * 256 + yo) * 256 + xo] = 0.5f * (a - bb - cc + d);
    }
}

// ---------------------------------------------------------------------------
// Finish channel means: br=0 -> amean (ct), br=1 -> am0 (lf).
// part[br][ (z*2+cog)*128 + j ][32]
// ---------------------------------------------------------------------------
__global__ __launch_bounds__(TPB) void meanfin_k(
    const float* __restrict__ part, float* __restrict__ amean, float* __restrict__ am0)
{
    const int br = blockIdx.x;
    const int o = threadIdx.x;                 // 0..255 -> z(4) x co(64)
    const int z = o >> 6, co = o & 63, cog = co >> 5, c = co & 31;
    const float* p = part + (size_t)br * 32768 + ((size_t)(z * 2 + cog) * 128) * 32 + c;
    float s = 0.f;
    for (int j = 0; j < 128; ++j) s += p[j * 32];
    (br ? am0 : amean)[z * 64 + co] = s * (1.f / 65536.f);
}

// ---------------------------------------------------------------------------
// t1->t2->t3 chain, blockIdx.x = b
// ---------------------------------------------------------------------------
__global__ __launch_bounds__(64) void tchain_k(
    const float* __restrict__ amean,
    const float* __restrict__ t1w, const float* __restrict__ t1b,
    const float* __restrict__ t2w, const float* __restrict__ t2b,
    const float* __restrict__ t3w, const float* __restrict__ t3b,
    float* __restrict__ theta)
{
    const int b = blockIdx.x;
    const float* am = amean + b * 64;
    __shared__ float a0[64], a1[64], a2[64];
    const int co = threadIdx.x;
    a0[co] = am[co];
    __syncthreads();
    float s = t1b[co];
    #pragma unroll 8
    for (int ci = 0; ci < 64; ++ci) s = fmaf(t1w[co * 64 + ci], a0[ci], s);
    a1[co] = fmaxf(s, 0.f);
    __syncthreads();
    s = t2b[co];
    #pragma unroll 8
    for (int ci = 0; ci < 64; ++ci) s = fmaf(t2w[co * 64 + ci], a1[ci], s);
    a2[co] = fmaxf(s, 0.f);
    __syncthreads();
    if (co == 0) {
        float v = t3b[0];
        for (int ci = 0; ci < 64; ++ci) v = fmaf(t3w[ci], a2[ci], v);
        theta[b] = 1.f / (1.f + expf(-v));
    }
}

// ---------------------------------------------------------------------------
// wave-per-output FC. ACT 0 relu, 1 sigmoid, 2 tanh.
// ---------------------------------------------------------------------------
template<int ACT>
__global__ __launch_bounds__(TPB) void fcw_k(
    const float* __restrict__ in, const float* __restrict__ w,
    const float* __restrict__ bias, float* __restrict__ out, int K, int N)
{
    const int lane = threadIdx.x & 63, wv = threadIdx.x >> 6;
    const int idx = blockIdx.x * 4 + wv;
    if (idx >= 4 * N) return;
    const int b = idx / N, co = idx % N;
    float s = 0.f;
    for (int k = lane * 4; k < K; k += 256) {
        const float4 wv4 = *(const float4*)(w + (size_t)co * K + k);
        const float4 iv  = *(const float4*)(in + (size_t)b * K + k);
        s += wv4.x * iv.x + wv4.y * iv.y + wv4.z * iv.z + wv4.w * iv.w;
    }
    #pragma unroll
    for (int o = 32; o > 0; o >>= 1) s += __shfl_xor(s, o, 64);
    if (lane == 0) {
        s += bias[co];
        if (ACT == 0) s = fmaxf(s, 0.f);
        else if (ACT == 1) s = 1.f / (1.f + expf(-s));
        else s = tanhf(s);
        out[(size_t)b * N + co] = s;
    }
}

// ---------------------------------------------------------------------------
extern "C" void kernel_launch(void* const* d_in, const int* in_sizes, int n_in,
                              void* d_out, int out_size, void* d_ws, size_t ws_size,
                              hipStream_t stream)
{
    const float* x      = (const float*)d_in[0];
    const float* cdc_w  = (const float*)d_in[11];
    const float* t1_w   = (const float*)d_in[14];
    const float* t1_b   = (const float*)d_in[15];
    const float* t2_w   = (const float*)d_in[16];
    const float* t2_b   = (const float*)d_in[17];
    const float* t3_w   = (const float*)d_in[18];
    const float* t3_b   = (const float*)d_in[19];
    const float* fc1_w  = (const float*)d_in[22];
    const float* fc1_b  = (const float*)d_in[23];
    const float* fc2_w  = (const float*)d_in[24];
    const float* fc2_b  = (const float*)d_in[25];
    const float* fc3_w  = (const float*)d_in[26];
    const float* fc3_b  = (const float*)d_in[27];
    const float* g_w    = (const float*)d_in[28];
    const float* g_b    = (const float*)d_in[29];
    const float* be_w   = (const float*)d_in[30];
    const float* be_b   = (const float*)d_in[31];

    float* out = (float*)d_out;

    // workspace layout (B2 region doubles as haarA/hf during phase A)
    ushortT* A2 = (ushortT*)d_ws;                  // 2 x 16.9 MB
    ushortT* B2 = A2 + 2 * PSTR;                   // 2 x 16.9 MB (aliased below)
    float* haarA = (float*)B2;                     // (4,3,256,256) - phase A only
    float* hf    = haarA + 786432;                 // (4,9,256,256) - phase A only
    float* part  = (float*)(B2 + 2 * PSTR);        // 2 x 32768
    float* amean = part + 65536;                   // 256
    float* am0   = amean + 256;                    // 256
    float* am1   = am0 + 256;                      // 2048
    float* am2   = am1 + 2048;
    float* am3   = am2 + 2048;
    float* theta = am3 + 2048;                     // 4
    float* gamma = theta + 4;                      // 128 [4][32]
    float* beta  = gamma + 128;                    // 128
    short* wpack = (short*)(beta + 128);           // 16 x 10240 shorts
    const size_t need_bytes = (size_t)((char*)(wpack + 16 * 10240) - (char*)d_ws);
    if (ws_size < need_bytes) return;

    const dim3 blk(TPB);

    // --- phase A: DWT, packs, ct/lf mean convs, scalar chains ---
    dwt_k<<<dim3((4 * 256 * 256 + TPB - 1) / TPB), blk, 0, stream>>>(x, haarA, hf);
    packall_k<<<dim3(12), dim3(64), 0, stream>>>(
        (const float*)d_in[1], (const float*)d_in[2], (const float*)d_in[3], (const float*)d_in[4],
        (const float*)d_in[5], (const float*)d_in[6], (const float*)d_in[7], (const float*)d_in[8],
        (const float*)d_in[9], (const float*)d_in[10], (const float*)d_in[32], (const float*)d_in[33],
        (const float*)d_in[34], (const float*)d_in[35], (const float*)d_in[36], (const float*)d_in[37],
        (const float*)d_in[12], (const float*)d_in[13], (const float*)d_in[20], (const float*)d_in[21],
        wpack);

    conv16_k<4><<<dim3(128, 2, 4), blk, 0, stream>>>(hf, wpack + 8 * 10240, nullptr, 0, part,
        9, 256, 256, 2, (long long)9 * 65536);
    conv16_k<4><<<dim3(128, 2, 4), blk, 0, stream>>>(haarA, wpack + 10 * 10240, nullptr, 0, part + 32768,
        3, 256, 256, 2, (long long)3 * 65536);

    // haarA/hf fully consumed -> safe to zero halos of all 4 padded buffers
    zero_k<<<dim3(513), blk, 0, stream>>>((unsigned int*)A2, (unsigned int*)B2);

    meanfin_k<<<dim3(2), blk, 0, stream>>>(part, amean, am0);
    tchain_k<<<dim3(4), dim3(64), 0, stream>>>(amean, t1_w, t1_b, t2_w, t2_b, t3_w, t3_b, theta);
    fcw_k<0><<<dim3(512), blk, 0, stream>>>(am0, fc1_w, fc1_b, am1, 64, 512);
    fcw_k<0><<<dim3(512), blk, 0, stream>>>(am1, fc2_w, fc2_b, am2, 512, 512);
    fcw_k<1><<<dim3(512), blk, 0, stream>>>(am2, fc3_w, fc3_b, am3, 512, 512);
    fcw_k<1><<<dim3(32), blk, 0, stream>>>(am3, g_w, g_b, gamma, 512, 32);
    fcw_k<2><<<dim3(32), blk, 0, stream>>>(am3, be_w, be_b, beta, 512, 32);
    packcdc_k<<<dim3(4), dim3(64), 0, stream>>>(cdc_w, theta, wpack);

    // --- heavy chain, two batch-pairs, z=2 batched ---
    const dim3 g512(512, 1, 2);
    for (int p = 0; p < 2; ++p) {
        const float* xp  = x + (size_t)(2 * p) * 3 * HW;
        float* outEp = out + (size_t)(2 * p) * 3 * HW;
        float* outMp = out + (size_t)4 * 3 * HW + (size_t)(2 * p) * HW;

        // enc1: fp32 NCHW -> NHWC bf16
        conv16_k<0><<<dim3(512, 1, 2), blk, 0, stream>>>(xp, wpack, A2, PSTR, nullptr, 3, 512, 512, 4, (long long)3 * HW);
        // enc2..enc5
        dconv_k<0><<<g512, blk, 0, stream>>>(A2, wpack + 1 * 10240, 0, B2, nullptr, nullptr, nullptr, nullptr, nullptr);
        dconv_k<0><<<g512, blk, 0, stream>>>(B2, wpack + 2 * 10240, 0, A2, nullptr, nullptr, nullptr, nullptr, nullptr);
        dconv_k<0><<<g512, blk, 0, stream>>>(A2, wpack + 3 * 10240, 0, B2, nullptr, nullptr, nullptr, nullptr, nullptr);
        dconv_k<0><<<g512, blk, 0, stream>>>(B2, wpack + 4 * 10240, 0, A2, nullptr, nullptr, nullptr, nullptr, nullptr);
        // cdc (theta folded per batch): A2 -> B2 = f_deco
        dconv_k<0><<<g512, blk, 0, stream>>>(A2, wpack + (size_t)(12 + 2 * p) * 10240, 10240, B2, nullptr, nullptr, nullptr, nullptr, nullptr);
        // res: B2 -> A2
        dconv_k<2><<<g512, blk, 0, stream>>>(B2, wpack + 5 * 10240, 0, A2, gamma + 64 * p, beta + 64 * p, nullptr, nullptr, nullptr);
        // d1: A2 -> B2
        dconv_k<0><<<g512, blk, 0, stream>>>(A2, wpack + 6 * 10240, 0, B2, nullptr, nullptr, nullptr, nullptr, nullptr);
        // d2 + tanh + enhance -> outputs
        dconv_k<3><<<g512, blk, 0, stream>>>(B2, wpack + 7 * 10240, 0, nullptr, nullptr, nullptr, xp, outEp, outMp);
    }
}

// Round 6
// 427.532 us; speedup vs baseline: 17.7093x; 1.4568x over previous
//
#include <hip/hip_runtime.h>
#include <hip/hip_bf16.h>
#include <cmath>

#define TPB 256

typedef __attribute__((ext_vector_type(8))) short s16x8;
typedef __attribute__((ext_vector_type(4))) float f32x4;
typedef unsigned short ushortT;

constexpr long long PSTR = 8454272;   // 514*514*32 ushorts per padded image
constexpr int HW = 512 * 512;

static __device__ __forceinline__ short f2bf(float f) {
    union { __hip_bfloat16 h; short s; } u;
    u.h = __float2bfloat16(f);
    return u.s;
}
static __device__ __forceinline__ float bf2f(unsigned short u) {
    union { unsigned int i; float f; } v;
    v.i = ((unsigned int)u) << 16;
    return v.f;
}
static __device__ __forceinline__ unsigned int pack2(float a, float b) {
    return (unsigned int)(unsigned short)f2bf(a) | ((unsigned int)(unsigned short)f2bf(b) << 16);
}

#define COMP(vec,k) ((k)==0?(vec).x:((k)==1?(vec).y:((k)==2?(vec).z:(vec).w)))

// ---------------------------------------------------------------------------
// Weight pack body. slot stride 10240 shorts; bias fp32 @ short-offset 9216.
// shorts[((t*2+mt)*64+lane)*8+i] = w[co=cog*32+16mt+(lane&15)][ci=8*(lane>>4)+i][t]
// cdc fold: center tap -= theta * sum_taps
// ---------------------------------------------------------------------------
static __device__ void pack_body(const float* w, const float* bias, const float* theta,
                                 short* dst, int CO, int CI, int cog, int l)
{
    const int l15 = l & 15, sl = l >> 4;
    for (int t = 0; t < 9; ++t) {
        for (int mt = 0; mt < 2; ++mt) {
            const int co = cog * 32 + 16 * mt + l15;
            s16x8 p;
            #pragma unroll
            for (int i = 0; i < 8; ++i) {
                const int ci = 8 * sl + i;
                float val = 0.f;
                if (co < CO && ci < CI) {
                    val = w[((size_t)co * CI + ci) * 9 + t];
                    if (theta && t == 4) {
                        float s = 0.f;
                        for (int tt = 0; tt < 9; ++tt) s += w[((size_t)co * CI + ci) * 9 + tt];
                        val -= theta[0] * s;
                    }
                }
                p[i] = f2bf(val);
            }
            *(s16x8*)(dst + ((size_t)(t * 2 + mt) * 64 + l) * 8) = p;
        }
    }
    if (l < 32) {
        const int co = cog * 32 + l;
        ((float*)(dst + 9216))[l] = (bias && co < CO) ? bias[co] : 0.f;
    }
}

__global__ __launch_bounds__(64) void packall_k(
    const float* e1w, const float* e1b, const float* e2w, const float* e2b,
    const float* e3w, const float* e3b, const float* e4w, const float* e4b,
    const float* e5w, const float* e5b, const float* resw, const float* resb,
    const float* d1w, const float* d1b, const float* d2w, const float* d2b,
    const float* ctw, const float* ctb, const float* lfw, const float* lfb,
    short* wpack)
{
    const int s = blockIdx.x;
    const float *w, *b;
    int CO = 32, CI = 32, cog = 0;
    switch (s) {
        case 0: w = e1w; b = e1b; CI = 3; break;
        case 1: w = e2w; b = e2b; break;
        case 2: w = e3w; b = e3b; break;
        case 3: w = e4w; b = e4b; break;
        case 4: w = e5w; b = e5b; break;
        case 5: w = resw; b = resb; break;
        case 6: w = d1w; b = d1b; break;
        case 7: w = d2w; b = d2b; CO = 1; break;
        case 8: case 9: w = ctw; b = ctb; CO = 64; CI = 9; cog = s - 8; break;
        default: w = lfw; b = lfb; CO = 64; CI = 3; cog = s - 10; break;
    }
    pack_body(w, b, nullptr, wpack + (size_t)s * 10240, CO, CI, cog, threadIdx.x);
}

__global__ __launch_bounds__(64) void packcdc_k(
    const float* cdcw, const float* theta, short* wpack)
{
    const int b = blockIdx.x;
    pack_body(cdcw, nullptr, theta + b, wpack + (size_t)(12 + b) * 10240, 32, 32, 0, threadIdx.x);
}

// ---------------------------------------------------------------------------
// zero halo rings of 8 padded NHWC buffers (A2 z0..3, B2 z0..3)
// ---------------------------------------------------------------------------
__global__ __launch_bounds__(TPB) void zero_k(unsigned int* A2u, unsigned int* B2u)
{
    const int idx = blockIdx.x * TPB + threadIdx.x;
    if (idx >= 8 * 32832) return;
    const int q = idx / 32832, r = idx % 32832;
    unsigned int* P = (q < 4 ? A2u : B2u) + (size_t)(q & 3) * 4227136;
    const int RSU = 514 * 16;
    int off;
    if (r < 8224)       off = r;
    else if (r < 16448) off = 513 * RSU + (r - 8224);
    else if (r < 24640) { int u = r - 16448; off = (1 + (u >> 4)) * RSU + (u & 15); }
    else                { int u = r - 24640; off = (1 + (u >> 4)) * RSU + 513 * 16 + (u & 15); }
    P[off] = 0u;
}

// ---------------------------------------------------------------------------
// LDS-staged MFMA conv (fp32 NCHW input): enc1 (EPI=0) / ct,lf (EPI=4).
// EPI 0: bias+relu -> padded NHWC bf16 (outP + z*bstr_outP)
// EPI 4: bias+relu -> per-block 32-channel partial sums (deterministic)
// ---------------------------------------------------------------------------
template<int EPI>
__global__ __launch_bounds__(TPB) void conv16_k(
    const float* __restrict__ in0, const short* __restrict__ wpack0,
    ushortT* __restrict__ outP0, long long bstr_outP, float* __restrict__ part,
    int CI, int H, int W, int ntx, long long bstr_in)
{
    constexpr int RSX = 130;
    constexpr int ROWB = RSX * 64;
    __shared__ s16x8 lds_t[6 * RSX * 4];
    __shared__ float s_red[4][32];
    char* sb = (char*)lds_t;

    const int tid  = threadIdx.x;
    const int lane = tid & 63;
    const int wv   = tid >> 6;
    const float* in = in0 + (size_t)blockIdx.z * bstr_in;
    const int cog  = blockIdx.y;
    const short* wslot = wpack0 + (size_t)cog * 10240;
    const int tx = blockIdx.x % ntx, tyb = blockIdx.x / ntx;
    const int x0g = tx * 128, y0 = tyb * 4;
    const size_t HWl = (size_t)H * W;

    s16x8 wf[9][2];
    #pragma unroll
    for (int t = 0; t < 9; ++t)
        #pragma unroll
        for (int mt = 0; mt < 2; ++mt)
            wf[t][mt] = *(const s16x8*)(wslot + ((size_t)(t * 2 + mt) * 64 + lane) * 8);

    for (int q = tid; q < 768; q += TPB) {
        const int xq = q & 31, o = (q >> 5) & 3, row = q >> 7;
        const int gy = y0 - 1 + row;
        const bool yok = (gy >= 0) && (gy < H);
        const float* gp = in + (size_t)gy * W + x0g + 4 * xq;
        float4 v[8];
        #pragma unroll
        for (int j = 0; j < 8; ++j) {
            const int ci = 8 * o + j;
            if (yok && ci < CI) v[j] = *(const float4*)(gp + (size_t)ci * HWl);
            else                v[j] = make_float4(0.f, 0.f, 0.f, 0.f);
        }
        #pragma unroll
        for (int k = 0; k < 4; ++k) {
            const int lx = 1 + 4 * xq + k;
            const int vs = (lx + (lx >> 2)) & 3;
            s16x8 p;
            #pragma unroll
            for (int j = 0; j < 8; ++j) p[j] = f2bf(COMP(v[j], k));
            *(s16x8*)(sb + (row * RSX + lx) * 64 + ((o ^ vs) << 4)) = p;
        }
    }
    if (tid < 48) {
        const int side = tid & 1, o = (tid >> 1) & 3, row = tid >> 3;
        const int gy = y0 - 1 + row;
        const int lx = side ? 129 : 0;
        const int gx = x0g + (side ? 128 : -1);
        const bool ok = (gy >= 0) && (gy < H) && (gx >= 0) && (gx < W);
        s16x8 p;
        #pragma unroll
        for (int j = 0; j < 8; ++j) {
            const int ci = 8 * o + j;
            p[j] = f2bf((ok && ci < CI) ? in[(size_t)ci * HWl + (size_t)gy * W + gx] : 0.f);
        }
        const int vs = (lx + (lx >> 2)) & 3;
        *(s16x8*)(sb + (row * RSX + lx) * 64 + ((o ^ vs) << 4)) = p;
    }
    __syncthreads();

    const int xw = 32 * wv;
    const int l15 = lane & 15, slot = lane >> 4;
    int roff[3][2];
    #pragma unroll
    for (int dx = 0; dx < 3; ++dx)
        #pragma unroll
        for (int nt = 0; nt < 2; ++nt) {
            const int lx = xw + 16 * nt + dx + l15;
            const int vs = (lx + (lx >> 2)) & 3;
            roff[dx][nt] = lx * 64 + ((slot ^ vs) << 4);
        }

    const float* bptr = (const float*)(wslot + 9216);
    float ps[2][4];
    #pragma unroll
    for (int mt = 0; mt < 2; ++mt)
        #pragma unroll
        for (int reg = 0; reg < 4; ++reg) ps[mt][reg] = 0.f;

    for (int r2 = 0; r2 < 4; r2 += 2) {
        f32x4 acc[2][2][2];
        #pragma unroll
        for (int a = 0; a < 2; ++a)
            #pragma unroll
            for (int b = 0; b < 2; ++b)
                #pragma unroll
                for (int c = 0; c < 2; ++c)
                    #pragma unroll
                    for (int e = 0; e < 4; ++e) acc[a][b][c][e] = 0.f;

        #pragma unroll
        for (int dy = 0; dy < 3; ++dy) {
            const int rb0 = (r2 + dy) * ROWB;
            #pragma unroll
            for (int dx = 0; dx < 3; ++dx) {
                const int t = dy * 3 + dx;
                #pragma unroll
                for (int nt = 0; nt < 2; ++nt) {
                    const s16x8 b0 = *(const s16x8*)(sb + rb0 + roff[dx][nt]);
                    const s16x8 b1 = *(const s16x8*)(sb + rb0 + ROWB + roff[dx][nt]);
                    #pragma unroll
                    for (int mt = 0; mt < 2; ++mt) {
                        acc[0][mt][nt] = __builtin_amdgcn_mfma_f32_16x16x32_bf16(wf[t][mt], b0, acc[0][mt][nt], 0, 0, 0);
                        acc[1][mt][nt] = __builtin_amdgcn_mfma_f32_16x16x32_bf16(wf[t][mt], b1, acc[1][mt][nt], 0, 0, 0);
                    }
                }
            }
        }

        #pragma unroll
        for (int rr = 0; rr < 2; ++rr) {
            const int gy = y0 + r2 + rr;
            #pragma unroll
            for (int mt = 0; mt < 2; ++mt)
                #pragma unroll
                for (int nt = 0; nt < 2; ++nt) {
                    const int gx = x0g + xw + 16 * nt + l15;
                    if constexpr (EPI == 0) {
                        ushortT* outP = outP0 + (size_t)blockIdx.z * bstr_outP;
                        float v[4];
                        #pragma unroll
                        for (int reg = 0; reg < 4; ++reg)
                            v[reg] = fmaxf(acc[rr][mt][nt][reg] + bptr[16 * mt + 4 * slot + reg], 0.f);
                        *(uint2*)(outP + ((size_t)(gy + 1) * 514 + gx + 1) * 32 + 16 * mt + 4 * slot) =
                            make_uint2(pack2(v[0], v[1]), pack2(v[2], v[3]));
                    } else {
                        #pragma unroll
                        for (int reg = 0; reg < 4; ++reg)
                            ps[mt][reg] += fmaxf(acc[rr][mt][nt][reg] + bptr[16 * mt + 4 * slot + reg], 0.f);
                    }
                }
        }
    }

    if constexpr (EPI == 4) {
        #pragma unroll
        for (int mt = 0; mt < 2; ++mt)
            #pragma unroll
            for (int reg = 0; reg < 4; ++reg) {
                #pragma unroll
                for (int o = 1; o < 16; o <<= 1)
                    ps[mt][reg] += __shfl_xor(ps[mt][reg], o, 64);
            }
        #pragma unroll
        for (int mt = 0; mt < 2; ++mt)
            #pragma unroll
            for (int reg = 0; reg < 4; ++reg)
                if (l15 == mt * 4 + reg)
                    s_red[wv][16 * mt + 4 * slot + reg] = ps[mt][reg];
        __syncthreads();
        if (tid < 32) {
            const float s = s_red[0][tid] + s_red[1][tid] + s_red[2][tid] + s_red[3][tid];
            part[(((size_t)blockIdx.z * gridDim.y + blockIdx.y) * gridDim.x + blockIdx.x) * 32 + tid] = s;
        }
    }
}

// ---------------------------------------------------------------------------
// LDS-staged MFMA conv on padded NHWC bf16 (no conversion, no bounds checks).
// Stage 6 x 130 x 32ch tile (49,920 B) with octet-swizzle, then conv16-style
// MFMA loop. z = blockIdx.z batch. EPI: 0 relu | 2 res | 3 d2+enhance.
// ---------------------------------------------------------------------------
template<int EPI>
__global__ __launch_bounds__(TPB) void dconvL_k(
    const ushortT* __restrict__ inP0, const short* __restrict__ wbase, int wstr,
    ushortT* __restrict__ outP0,
    const float* __restrict__ gamma0, const float* __restrict__ beta0,
    const float* __restrict__ xorig0, float* __restrict__ outE0, float* __restrict__ outM0)
{
    constexpr int MT = (EPI == 3) ? 1 : 2;
    constexpr int RSX = 130;
    constexpr int ROWB = RSX * 64;
    __shared__ s16x8 lds_t[6 * RSX * 4];   // 49,920 B
    char* sb = (char*)lds_t;

    const int z = blockIdx.z;
    const ushortT* inP = inP0 + (size_t)z * PSTR;
    const short* wslot = wbase + (size_t)z * wstr;

    const int tid = threadIdx.x, lane = tid & 63, wv = tid >> 6;
    const int bid = blockIdx.x;
    const int swz = (bid & 7) * 64 + (bid >> 3);   // XCD-contiguous y-tiles
    const int x0 = (swz & 3) * 128, y0 = (swz >> 2) * 4;
    const int l15 = lane & 15, slot = lane >> 4;

    s16x8 wf[9][MT];
    #pragma unroll
    for (int t = 0; t < 9; ++t)
        #pragma unroll
        for (int mt = 0; mt < MT; ++mt)
            wf[t][mt] = *(const s16x8*)(wslot + ((size_t)(t * 2 + mt) * 64 + lane) * 8);

    // --- stage: 3120 16B chunks; chunk p=(row*130+lx)*4+osl holds global
    // octet o = osl ^ vs(lx)  (so compute reads slot' = slot ^ vs) ---
    #pragma unroll
    for (int it = 0; it < 12; ++it) {
        const int p = it * 256 + tid;
        const int row = p / 520;
        const int rem = p - row * 520;
        const int lx = rem >> 2, osl = rem & 3;
        const int o = osl ^ ((lx + (lx >> 2)) & 3);
        const uint4 v = *(const uint4*)(inP + ((size_t)(y0 + row) * 514 + x0 + lx) * 32 + o * 8);
        *(uint4*)(sb + p * 16) = v;
    }
    if (tid < 48) {
        const int p = 3072 + tid;
        const int row = p / 520;
        const int rem = p - row * 520;
        const int lx = rem >> 2, osl = rem & 3;
        const int o = osl ^ ((lx + (lx >> 2)) & 3);
        *(uint4*)(sb + p * 16) = *(const uint4*)(inP + ((size_t)(y0 + row) * 514 + x0 + lx) * 32 + o * 8);
    }
    __syncthreads();

    const int xw = 32 * wv;
    int roff[3][2];
    #pragma unroll
    for (int dx = 0; dx < 3; ++dx)
        #pragma unroll
        for (int nt = 0; nt < 2; ++nt) {
            const int lx = xw + 16 * nt + dx + l15;
            const int vs = (lx + (lx >> 2)) & 3;
            roff[dx][nt] = lx * 64 + ((slot ^ vs) << 4);
        }
    const float* bptr = (const float*)(wslot + 9216);

    #pragma unroll
    for (int r2 = 0; r2 < 4; r2 += 2) {
        f32x4 acc[2][MT][2];
        #pragma unroll
        for (int a = 0; a < 2; ++a)
            #pragma unroll
            for (int b = 0; b < MT; ++b)
                #pragma unroll
                for (int c = 0; c < 2; ++c)
                    #pragma unroll
                    for (int e = 0; e < 4; ++e) acc[a][b][c][e] = 0.f;

        #pragma unroll
        for (int dy = 0; dy < 3; ++dy) {
            const int rb0 = (r2 + dy) * ROWB;
            #pragma unroll
            for (int dx = 0; dx < 3; ++dx) {
                const int t = dy * 3 + dx;
                #pragma unroll
                for (int nt = 0; nt < 2; ++nt) {
                    const s16x8 b0 = *(const s16x8*)(sb + rb0 + roff[dx][nt]);
                    const s16x8 b1 = *(const s16x8*)(sb + rb0 + ROWB + roff[dx][nt]);
                    #pragma unroll
                    for (int mt = 0; mt < MT; ++mt) {
                        acc[0][mt][nt] = __builtin_amdgcn_mfma_f32_16x16x32_bf16(wf[t][mt], b0, acc[0][mt][nt], 0, 0, 0);
                        acc[1][mt][nt] = __builtin_amdgcn_mfma_f32_16x16x32_bf16(wf[t][mt], b1, acc[1][mt][nt], 0, 0, 0);
                    }
                }
            }
        }

        #pragma unroll
        for (int rr = 0; rr < 2; ++rr) {
            const int gy = y0 + r2 + rr;
            if constexpr (EPI == 3) {
                if (slot == 0) {
                    const float* xorig = xorig0 + (size_t)z * 3 * HW;
                    float* outE = outE0 + (size_t)z * 3 * HW;
                    float* outM = outM0 + (size_t)z * HW;
                    const float b0v = bptr[0];
                    #pragma unroll
                    for (int nt = 0; nt < 2; ++nt) {
                        const int gx = x0 + xw + 16 * nt + l15;
                        const float om = tanhf(acc[rr][0][nt][0] + b0v);
                        outM[(size_t)gy * 512 + gx] = om;
                        #pragma unroll
                        for (int c = 0; c < 3; ++c) {
                            const size_t xi = ((size_t)c * 512 + gy) * 512 + gx;
                            const float xv = xorig[xi];
                            outE[xi] = xv + om * (xv * xv - xv);
                        }
                    }
                }
            } else {
                ushortT* outP = outP0 + (size_t)z * PSTR;
                #pragma unroll
                for (int mt = 0; mt < MT; ++mt)
                    #pragma unroll
                    for (int nt = 0; nt < 2; ++nt) {
                        const int gx = x0 + xw + 16 * nt + l15;
                        const size_t off = ((size_t)(gy + 1) * 514 + gx + 1) * 32 + 16 * mt + 4 * slot;
                        float v[4];
                        #pragma unroll
                        for (int reg = 0; reg < 4; ++reg)
                            v[reg] = acc[rr][mt][nt][reg] + bptr[16 * mt + 4 * slot + reg];
                        if constexpr (EPI == 0) {
                            #pragma unroll
                            for (int reg = 0; reg < 4; ++reg) v[reg] = fmaxf(v[reg], 0.f);
                        } else if constexpr (EPI == 2) {
                            const float* gamma = gamma0 + 32 * z;
                            const float* beta  = beta0 + 32 * z;
                            const uint2 din = *(const uint2*)(inP + off);
                            const int cb = 16 * mt + 4 * slot;
                            v[0] = bf2f((unsigned short)(din.x & 0xffff)) + gamma[cb + 0] * v[0] + beta[cb + 0];
                            v[1] = bf2f((unsigned short)(din.x >> 16))    + gamma[cb + 1] * v[1] + beta[cb + 1];
                            v[2] = bf2f((unsigned short)(din.y & 0xffff)) + gamma[cb + 2] * v[2] + beta[cb + 2];
                            v[3] = bf2f((unsigned short)(din.y >> 16))    + gamma[cb + 3] * v[3] + beta[cb + 3];
                        }
                        *(uint2*)(outP + off) = make_uint2(pack2(v[0], v[1]), pack2(v[2], v[3]));
                    }
            }
        }
    }
}

// ---------------------------------------------------------------------------
// Haar DWT (all 4 batches)
// ---------------------------------------------------------------------------
__global__ __launch_bounds__(TPB) void dwt_k(
    const float* __restrict__ x, float* __restrict__ haarA, float* __restrict__ hf)
{
    const int idx = blockIdx.x * TPB + threadIdx.x;
    if (idx >= 4 * 256 * 256) return;
    const int xo = idx & 255;
    const int yo = (idx >> 8) & 255;
    const int b  = idx >> 16;
    #pragma unroll
    for (int c = 0; c < 3; ++c) {
        const float* p = x + (((size_t)b * 3 + c) * 512 + 2 * yo) * 512 + 2 * xo;
        const float a = p[0], bb = p[1], cc = p[512], d = p[513];
        haarA[(((size_t)b * 3 + c) * 256 + yo) * 256 + xo] = 0.5f * (a + bb + cc + d);
        hf[(((size_t)b * 9 + 0 + c) * 256 + yo) * 256 + xo] = 0.5f * (a + bb - cc - d);
        hf[(((size_t)b * 9 + 3 + c) * 256 + yo) * 256 + xo] = 0.5f * (a - bb + cc - d);
        hf[(((size_t)b * 9 + 6 + c) * 256 + yo) * 256 + xo] = 0.5f * (a - bb - cc + d);
    }
}

// ---------------------------------------------------------------------------
// Finish channel means: br=0 -> amean (ct), br=1 -> am0 (lf).
// ---------------------------------------------------------------------------
__global__ __launch_bounds__(TPB) void meanfin_k(
    const float* __restrict__ part, float* __restrict__ amean, float* __restrict__ am0)
{
    const int br = blockIdx.x;
    const int o = threadIdx.x;
    const int z = o >> 6, co = o & 63, cog = co >> 5, c = co & 31;
    const float* p = part + (size_t)br * 32768 + ((size_t)(z * 2 + cog) * 128) * 32 + c;
    float s = 0.f;
    for (int j = 0; j < 128; ++j) s += p[j * 32];
    (br ? am0 : amean)[z * 64 + co] = s * (1.f / 65536.f);
}

// ---------------------------------------------------------------------------
// t1->t2->t3 chain, blockIdx.x = b
// ---------------------------------------------------------------------------
__global__ __launch_bounds__(64) void tchain_k(
    const float* __restrict__ amean,
    const float* __restrict__ t1w, const float* __restrict__ t1b,
    const float* __restrict__ t2w, const float* __restrict__ t2b,
    const float* __restrict__ t3w, const float* __restrict__ t3b,
    float* __restrict__ theta)
{
    const int b = blockIdx.x;
    const float* am = amean + b * 64;
    __shared__ float a0[64], a1[64], a2[64];
    const int co = threadIdx.x;
    a0[co] = am[co];
    __syncthreads();
    float s = t1b[co];
    #pragma unroll 8
    for (int ci = 0; ci < 64; ++ci) s = fmaf(t1w[co * 64 + ci], a0[ci], s);
    a1[co] = fmaxf(s, 0.f);
    __syncthreads();
    s = t2b[co];
    #pragma unroll 8
    for (int ci = 0; ci < 64; ++ci) s = fmaf(t2w[co * 64 + ci], a1[ci], s);
    a2[co] = fmaxf(s, 0.f);
    __syncthreads();
    if (co == 0) {
        float v = t3b[0];
        for (int ci = 0; ci < 64; ++ci) v = fmaf(t3w[ci], a2[ci], v);
        theta[b] = 1.f / (1.f + expf(-v));
    }
}

// ---------------------------------------------------------------------------
// wave-per-output FC. ACT 0 relu, 1 sigmoid, 2 tanh.
// ---------------------------------------------------------------------------
template<int ACT>
__global__ __launch_bounds__(TPB) void fcw_k(
    const float* __restrict__ in, const float* __restrict__ w,
    const float* __restrict__ bias, float* __restrict__ out, int K, int N)
{
    const int lane = threadIdx.x & 63, wv = threadIdx.x >> 6;
    const int idx = blockIdx.x * 4 + wv;
    if (idx >= 4 * N) return;
    const int b = idx / N, co = idx % N;
    float s = 0.f;
    for (int k = lane * 4; k < K; k += 256) {
        const float4 wv4 = *(const float4*)(w + (size_t)co * K + k);
        const float4 iv  = *(const float4*)(in + (size_t)b * K + k);
        s += wv4.x * iv.x + wv4.y * iv.y + wv4.z * iv.z + wv4.w * iv.w;
    }
    #pragma unroll
    for (int o = 32; o > 0; o >>= 1) s += __shfl_xor(s, o, 64);
    if (lane == 0) {
        s += bias[co];
        if (ACT == 0) s = fmaxf(s, 0.f);
        else if (ACT == 1) s = 1.f / (1.f + expf(-s));
        else s = tanhf(s);
        out[(size_t)b * N + co] = s;
    }
}

// ---------------------------------------------------------------------------
extern "C" void kernel_launch(void* const* d_in, const int* in_sizes, int n_in,
                              void* d_out, int out_size, void* d_ws, size_t ws_size,
                              hipStream_t stream)
{
    const float* x      = (const float*)d_in[0];
    const float* cdc_w  = (const float*)d_in[11];
    const float* t1_w   = (const float*)d_in[14];
    const float* t1_b   = (const float*)d_in[15];
    const float* t2_w   = (const float*)d_in[16];
    const float* t2_b   = (const float*)d_in[17];
    const float* t3_w   = (const float*)d_in[18];
    const float* t3_b   = (const float*)d_in[19];
    const float* fc1_w  = (const float*)d_in[22];
    const float* fc1_b  = (const float*)d_in[23];
    const float* fc2_w  = (const float*)d_in[24];
    const float* fc2_b  = (const float*)d_in[25];
    const float* fc3_w  = (const float*)d_in[26];
    const float* fc3_b  = (const float*)d_in[27];
    const float* g_w    = (const float*)d_in[28];
    const float* g_b    = (const float*)d_in[29];
    const float* be_w   = (const float*)d_in[30];
    const float* be_b   = (const float*)d_in[31];

    float* out = (float*)d_out;

    // workspace layout: A2/B2 are 4-image padded NHWC ping-pong (67.6 MB each);
    // haarA/hf alias the B2 region (consumed before B2's first write)
    ushortT* A2 = (ushortT*)d_ws;                  // 4 x 16.9 MB
    ushortT* B2 = A2 + 4 * PSTR;                   // 4 x 16.9 MB
    float* haarA = (float*)B2;                     // (4,3,256,256) phase A only
    float* hf    = haarA + 786432;                 // (4,9,256,256) phase A only
    float* part  = (float*)(B2 + 4 * PSTR);        // 2 x 32768
    float* amean = part + 65536;                   // 256
    float* am0   = amean + 256;                    // 256
    float* am1   = am0 + 256;                      // 2048
    float* am2   = am1 + 2048;
    float* am3   = am2 + 2048;
    float* theta = am3 + 2048;                     // 4
    float* gamma = theta + 4;                      // 128 [4][32]
    float* beta  = gamma + 128;                    // 128
    short* wpack = (short*)(beta + 128);           // 16 x 10240 shorts
    const size_t need_bytes = (size_t)((char*)(wpack + 16 * 10240) - (char*)d_ws);
    if (ws_size < need_bytes) return;

    const dim3 blk(TPB);

    // --- phase A: DWT, packs, ct/lf mean convs, scalar chains ---
    dwt_k<<<dim3((4 * 256 * 256 + TPB - 1) / TPB), blk, 0, stream>>>(x, haarA, hf);
    packall_k<<<dim3(12), dim3(64), 0, stream>>>(
        (const float*)d_in[1], (const float*)d_in[2], (const float*)d_in[3], (const float*)d_in[4],
        (const float*)d_in[5], (const float*)d_in[6], (const float*)d_in[7], (const float*)d_in[8],
        (const float*)d_in[9], (const float*)d_in[10], (const float*)d_in[32], (const float*)d_in[33],
        (const float*)d_in[34], (const float*)d_in[35], (const float*)d_in[36], (const float*)d_in[37],
        (const float*)d_in[12], (const float*)d_in[13], (const float*)d_in[20], (const float*)d_in[21],
        wpack);

    conv16_k<4><<<dim3(128, 2, 4), blk, 0, stream>>>(hf, wpack + 8 * 10240, nullptr, 0, part,
        9, 256, 256, 2, (long long)9 * 65536);
    conv16_k<4><<<dim3(128, 2, 4), blk, 0, stream>>>(haarA, wpack + 10 * 10240, nullptr, 0, part + 32768,
        3, 256, 256, 2, (long long)3 * 65536);

    // haarA/hf fully consumed -> zero halos of all 8 padded buffers
    zero_k<<<dim3((8 * 32832 + TPB - 1) / TPB), blk, 0, stream>>>((unsigned int*)A2, (unsigned int*)B2);

    meanfin_k<<<dim3(2), blk, 0, stream>>>(part, amean, am0);
    tchain_k<<<dim3(4), dim3(64), 0, stream>>>(amean, t1_w, t1_b, t2_w, t2_b, t3_w, t3_b, theta);
    fcw_k<0><<<dim3(512), blk, 0, stream>>>(am0, fc1_w, fc1_b, am1, 64, 512);
    fcw_k<0><<<dim3(512), blk, 0, stream>>>(am1, fc2_w, fc2_b, am2, 512, 512);
    fcw_k<1><<<dim3(512), blk, 0, stream>>>(am2, fc3_w, fc3_b, am3, 512, 512);
    fcw_k<1><<<dim3(32), blk, 0, stream>>>(am3, g_w, g_b, gamma, 512, 32);
    fcw_k<2><<<dim3(32), blk, 0, stream>>>(am3, be_w, be_b, beta, 512, 32);
    packcdc_k<<<dim3(4), dim3(64), 0, stream>>>(cdc_w, theta, wpack);

    // --- heavy chain, all 4 batches z-batched ---
    const dim3 g512(512, 1, 4);
    float* outM = out + (size_t)4 * 3 * HW;

    // enc1: fp32 NCHW -> NHWC bf16
    conv16_k<0><<<g512, blk, 0, stream>>>(x, wpack, A2, PSTR, nullptr, 3, 512, 512, 4, (long long)3 * HW);
    // enc2..enc5
    dconvL_k<0><<<g512, blk, 0, stream>>>(A2, wpack + 1 * 10240, 0, B2, nullptr, nullptr, nullptr, nullptr, nullptr);
    dconvL_k<0><<<g512, blk, 0, stream>>>(B2, wpack + 2 * 10240, 0, A2, nullptr, nullptr, nullptr, nullptr, nullptr);
    dconvL_k<0><<<g512, blk, 0, stream>>>(A2, wpack + 3 * 10240, 0, B2, nullptr, nullptr, nullptr, nullptr, nullptr);
    dconvL_k<0><<<g512, blk, 0, stream>>>(B2, wpack + 4 * 10240, 0, A2, nullptr, nullptr, nullptr, nullptr, nullptr);
    // cdc (theta folded per batch): A2 -> B2 = f_deco
    dconvL_k<0><<<g512, blk, 0, stream>>>(A2, wpack + 12 * 10240, 10240, B2, nullptr, nullptr, nullptr, nullptr, nullptr);
    // res: B2 -> A2
    dconvL_k<2><<<g512, blk, 0, stream>>>(B2, wpack + 5 * 10240, 0, A2, gamma, beta, nullptr, nullptr, nullptr);
    // d1: A2 -> B2
    dconvL_k<0><<<g512, blk, 0, stream>>>(A2, wpack + 6 * 10240, 0, B2, nullptr, nullptr, nullptr, nullptr, nullptr);
    // d2 + tanh + enhance -> outputs
    dconvL_k<3><<<g512, blk, 0, stream>>>(B2, wpack + 7 * 10240, 0, nullptr, nullptr, nullptr, x, out, outM);
}